// Round 8
// baseline (2141.770 us; speedup 1.0000x reference)
//
#include <hip/hip_runtime.h>
#include <hip/hip_bf16.h>
#include <math.h>

typedef __attribute__((ext_vector_type(8))) short short8;
typedef __attribute__((ext_vector_type(4))) float f32x4;
typedef __hip_bfloat16 bf16;

#define BB 2
#define TT 16
#define SSQ 257
#define DIMD 512
#define NROWS 8224          // B*T*S
#define DII 1365
#define DI2 2730
#define FNPAD 2816          // ff_in N padded (22*128), block-16 interleaved a/g
#define GLULD 1408          // glu row stride / ff_out K (44*32)
#define SKP 288             // padded key count for space attn
#define EPSR 1.1920929e-07f

__device__ __forceinline__ void async16(const void* g, const void* l) {
    __builtin_amdgcn_global_load_lds(
        (const __attribute__((address_space(1))) void*)g,
        (__attribute__((address_space(3))) void*)l, 16, 0, 0);
}

__device__ __forceinline__ short f2bfs(float x) {
    bf16 h = __float2bfloat16(x);
    return *reinterpret_cast<short*>(&h);
}

// fast exact-gelu: a * g * Phi(g), erf via A&S 7.1.26 (abs err 1.5e-7)
__device__ __forceinline__ float glu_fast(float a, float g) {
    float x = g * 0.70710678118654752f;
    float ax = fabsf(x);
    float t = __builtin_amdgcn_rcpf(__builtin_fmaf(0.3275911f, ax, 1.f));
    float p = t * (0.254829592f + t * (-0.284496736f + t * (1.421413741f
              + t * (-1.453152027f + t * 1.061405429f))));
    float erfv = 1.f - p * __expf(-ax * ax);
    erfv = (x < 0.f) ? -erfv : erfv;
    return a * 0.5f * g * (1.f + erfv);
}

// ---------------- batched per-layer weight transpose fp32->bf16 ----------------
// win interleave: a_j -> col (j>>4)*32 + (j&15); g_j -> col (j>>4)*32 + 16 + (j&15)
__global__ void wtrans_layer(const float* __restrict__ wq, const float* __restrict__ wk,
                             const float* __restrict__ wv, const float* __restrict__ wo,
                             const float* __restrict__ win, const float* __restrict__ wout,
                             bf16* __restrict__ dqkv, bf16* __restrict__ dwo,
                             bf16* __restrict__ dwin, bf16* __restrict__ dwout) {
    __shared__ float tile[32][33];
    int bid = blockIdx.x;
    const float* src; bf16* dst; int K, M, Kpad, interleave = 0, local;
    if (bid < 512)       { src = wq;   dst = dqkv;            K = 512;  M = 1024; Kpad = 512;  local = bid; }
    else if (bid < 768)  { src = wk;   dst = dqkv + 1024*512; K = 512;  M = 512;  Kpad = 512;  local = bid - 512; }
    else if (bid < 1024) { src = wv;   dst = dqkv + 1536*512; K = 512;  M = 512;  Kpad = 512;  local = bid - 768; }
    else if (bid < 1536) { src = wo;   dst = dwo;             K = 1024; M = 512;  Kpad = 1024; local = bid - 1024; }
    else if (bid < 2944) { src = win;  dst = dwin;            K = 512;  M = 2730; Kpad = 512;  local = bid - 1536; interleave = 1; }
    else                 { src = wout; dst = dwout;           K = 1365; M = 512;  Kpad = 1408; local = bid - 2944; }
    int tilesx = Kpad >> 5;
    int k0 = (local % tilesx) * 32, m0 = (local / tilesx) * 32;
    int tx = threadIdx.x & 31, ty = threadIdx.x >> 5;
    #pragma unroll
    for (int i = 0; i < 4; ++i) {
        int k = k0 + ty + 8 * i, m = m0 + tx;
        tile[ty + 8 * i][tx] = (k < K && m < M) ? src[(size_t)k * M + m] : 0.f;
    }
    __syncthreads();
    #pragma unroll
    for (int i = 0; i < 4; ++i) {
        int n = m0 + ty + 8 * i, k = k0 + tx;
        int nd = n;
        if (interleave) {
            if (n < DII)        nd = ((n >> 4) << 5) + (n & 15);
            else if (n < DI2) { int m = n - DII; nd = ((m >> 4) << 5) + 16 + (m & 15); }
            else              { int q = n - DI2; int j = DII + (q >> 1);
                                nd = ((j >> 4) << 5) + ((q & 1) << 4) + (j & 15); }
        }
        dst[(size_t)nd * Kpad + k] = __float2bfloat16(tile[tx][ty + 8 * i]);
    }
}

// ---------------- RMSNorm: one wave per row, float4 loads, shuffle reduce ----------------
template<int BF16OUT>
__global__ __launch_bounds__(256)
void rms_kernel(const float* __restrict__ x, const float* __restrict__ w,
                void* __restrict__ out, int perm) {
    int wave = threadIdx.x >> 6, lane = threadIdx.x & 63;
    int r = blockIdx.x * 4 + wave;
    int src = r;
    if (perm) {
        int t = r & 15; int rs = r >> 4; int s = rs % SSQ; int b = rs / SSQ;
        src = (b * TT + t) * SSQ + s;
    }
    const float4* xr = (const float4*)(x + (size_t)src * DIMD) + lane * 2;
    float4 a = xr[0], c = xr[1];
    float ss = a.x*a.x + a.y*a.y + a.z*a.z + a.w*a.w
             + c.x*c.x + c.y*c.y + c.z*c.z + c.w*c.w;
    ss += __shfl_xor(ss, 1);  ss += __shfl_xor(ss, 2);  ss += __shfl_xor(ss, 4);
    ss += __shfl_xor(ss, 8);  ss += __shfl_xor(ss, 16); ss += __shfl_xor(ss, 32);
    float sc = rsqrtf(ss * (1.f / DIMD) + EPSR);
    const float4* wr = (const float4*)w + lane * 2;
    float4 wa = wr[0], wb = wr[1];
    if (BF16OUT) {
        short8 v;
        v[0] = f2bfs(a.x * sc * wa.x); v[1] = f2bfs(a.y * sc * wa.y);
        v[2] = f2bfs(a.z * sc * wa.z); v[3] = f2bfs(a.w * sc * wa.w);
        v[4] = f2bfs(c.x * sc * wb.x); v[5] = f2bfs(c.y * sc * wb.y);
        v[6] = f2bfs(c.z * sc * wb.z); v[7] = f2bfs(c.w * sc * wb.w);
        *(short8*)((bf16*)out + (size_t)r * DIMD + lane * 8) = v;
    } else {
        float4* o = (float4*)((float*)out + (size_t)r * DIMD) + lane * 2;
        float4 o0 = {a.x * sc * wa.x, a.y * sc * wa.y, a.z * sc * wa.z, a.w * sc * wa.w};
        float4 o1 = {c.x * sc * wb.x, c.y * sc * wb.y, c.z * sc * wb.z, c.w * sc * wb.w};
        o[0] = o0; o[1] = o1;
    }
}

// ---------------- panel MFMA GEMM: B-panel resident in LDS, barrier-free loop --------
// K=512: full 128-col B panel = 128KB = one LDS, loaded once (transposed granule
// layout). No barriers after: each of 8 waves streams its own m-frags, A direct
// from global (L2/L3-hot, XCD-swizzled), 1-deep A prefetch, 8 MFMA per K-step.
// EPI: 1 = qkv + fused l2norm/gamma/rotary; 2 = glu (block-16 interleaved a/g).
template<int EPI>
__global__ __launch_bounds__(512, 1)
void mfma_gemm_panel(const bf16* __restrict__ A, int lda,
                     const bf16* __restrict__ Bt, int ldb,
                     const float* __restrict__ bias,
                     void* __restrict__ C, int ldc,
                     int nrow, int mchunk,
                     const float* __restrict__ qg, const float* __restrict__ kg,
                     int rotary) {
    __shared__ __align__(16) short lds_b[128 * 512];   // 128 KB
    // T1: bijective XCD-aware remap (m204)
    int gx = gridDim.x;
    int nwg = gx * gridDim.y;
    int lin = blockIdx.y * gx + blockIdx.x;
    int q8 = nwg >> 3, r8 = nwg & 7;
    int xcd = lin & 7, idx = lin >> 3;
    int wsw = (xcd < r8 ? xcd * (q8 + 1) : r8 * (q8 + 1) + (xcd - r8) * q8) + idx;
    int bx = wsw % gx, by = wsw / gx;
    int n0 = bx * 128, m0 = by * mchunk;

    int tid = threadIdx.x;
    int wave = tid >> 6, lane = tid & 63;
    int quad = lane >> 4, l16 = lane & 15;

    // stage B panel: 8192 granules of 16B; granule gi: c = gi>>7, n = gi&127
    const short* Bp = (const short*)Bt;
    #pragma unroll
    for (int j = 0; j < 16; ++j) {
        int gi = tid + 512 * j;
        int n = gi & 127, c = gi >> 7;
        async16(Bp + (size_t)(n0 + n) * ldb + c * 8, &lds_b[gi * 8]);
    }
    const short* Ap = (const short*)A;

    // hoisted epilogue constants
    float gl[2][4];
    float c0r[4], s0r[4], c1r[4], s1r[4];
    bool isqk = false;
    float ba[4], bg[4];
    if constexpr (EPI == 1) {
        int headb = n0 >> 6;
        isqk = headb < 24;
        if (isqk) {
            #pragma unroll
            for (int hh = 0; hh < 2; ++hh) {
                int head = headb + hh;
                const float* g = head < 16 ? qg + head * 64 : kg + (head - 16) * 64;
                gl[hh][0] = (g[l16] + 1.f) * 8.f;
                gl[hh][1] = (g[16 + l16] + 1.f) * 8.f;
                gl[hh][2] = (g[32 + l16] + 1.f) * 8.f;
                gl[hh][3] = (g[48 + l16] + 1.f) * 8.f;
            }
        }
        if (rotary) {
            float inv0 = __expf(-(float)l16 * 0.28782313662425572f);        // ln(1e4)/32
            float inv1 = __expf(-(float)(l16 + 16) * 0.28782313662425572f);
            #pragma unroll
            for (int e = 0; e < 4; ++e) {
                float t = (float)(quad * 4 + e);
                c0r[e] = __cosf(t * inv0); s0r[e] = __sinf(t * inv0);
                c1r[e] = __cosf(t * inv1); s1r[e] = __sinf(t * inv1);
            }
        }
    } else {
        int jb = n0 >> 1;
        #pragma unroll
        for (int t = 0; t < 4; ++t) {
            int j = jb + t * 16 + l16;
            ba[t] = (j < DII) ? bias[j] : 0.f;
            bg[t] = (j < DII) ? bias[DII + j] : 0.f;
        }
    }
    __syncthreads();   // B panel resident (drains vmcnt before barrier)

    int base_b = (quad * 128 + l16) * 16;   // byte addr of granule (c=quad, n=l16)
    int nfrag = mchunk >> 4;
    for (int f = wave; f < nfrag; f += 8) {
        int mrow = m0 + f * 16 + l16;
        if (mrow >= nrow) mrow = nrow - 1;          // clamp; C-write guarded below
        const short* ap = Ap + (size_t)mrow * lda + quad * 8;
        f32x4 acc[8];
        #pragma unroll
        for (int nj = 0; nj < 8; ++nj) acc[nj] = {0.f, 0.f, 0.f, 0.f};
        short8 a = *(const short8*)ap;
        short8 anext = a;
        #pragma unroll
        for (int kt = 0; kt < 16; ++kt) {
            if (kt < 15) anext = *(const short8*)(ap + (kt + 1) * 32);
            const char* vb = (const char*)lds_b + base_b + kt * 8192;
            __builtin_amdgcn_s_setprio(1);
            #pragma unroll
            for (int nj = 0; nj < 8; ++nj) {
                short8 b = *(const short8*)(vb + nj * 256);
                acc[nj] = __builtin_amdgcn_mfma_f32_16x16x32_bf16(a, b, acc[nj], 0, 0, 0);
            }
            __builtin_amdgcn_s_setprio(0);
            a = anext;
        }
        if constexpr (EPI == 1) {
            #pragma unroll
            for (int hh = 0; hh < 2; ++hh) {
                #pragma unroll
                for (int e = 0; e < 4; ++e) {
                    int row = m0 + f * 16 + quad * 4 + e;
                    float v0 = acc[hh * 4 + 0][e], v1 = acc[hh * 4 + 1][e];
                    float v2 = acc[hh * 4 + 2][e], v3 = acc[hh * 4 + 3][e];
                    if (isqk) {
                        float ss = v0 * v0 + v1 * v1 + v2 * v2 + v3 * v3;
                        ss += __shfl_xor(ss, 1); ss += __shfl_xor(ss, 2);
                        ss += __shfl_xor(ss, 4); ss += __shfl_xor(ss, 8);
                        float invn = 1.f / fmaxf(sqrtf(ss), 1e-12f);
                        v0 *= invn * gl[hh][0]; v1 *= invn * gl[hh][1];
                        v2 *= invn * gl[hh][2]; v3 *= invn * gl[hh][3];
                        if (rotary) {
                            float n0v = v0 * c0r[e] - v2 * s0r[e];
                            float n1v = v1 * c1r[e] - v3 * s1r[e];
                            float n2v = v2 * c0r[e] + v0 * s0r[e];
                            float n3v = v3 * c1r[e] + v1 * s1r[e];
                            v0 = n0v; v1 = n1v; v2 = n2v; v3 = n3v;
                        }
                    }
                    if (row < nrow) {
                        bf16* p = (bf16*)C + (size_t)row * ldc + n0 + hh * 64 + l16;
                        p[0]  = __float2bfloat16(v0);
                        p[16] = __float2bfloat16(v1);
                        p[32] = __float2bfloat16(v2);
                        p[48] = __float2bfloat16(v3);
                    }
                }
            }
        } else {
            int jb = n0 >> 1;
            #pragma unroll
            for (int e = 0; e < 4; ++e) {
                int row = m0 + f * 16 + quad * 4 + e;
                if (row < nrow) {
                    bf16* cr = (bf16*)C + (size_t)row * ldc;
                    #pragma unroll
                    for (int t = 0; t < 4; ++t)
                        cr[jb + t * 16 + l16] = __float2bfloat16(
                            glu_fast(acc[2 * t][e] + ba[t], acc[2 * t + 1][e] + bg[t]));
                }
            }
        }
    }
}

// ---------------- panel MFMA GEMM, fp32-accumulate: 64-col B panel, runtime K --------
// C[orow][n0..n0+64] += A[:, koff..koff+K] @ Bt[n0.., koff..koff+K]^T (+bias once).
// Same barrier-free streaming as mfma_gemm_panel. Used for wo (K=1024) and
// ff_out (K-split 1024 + 384, bias on first launch only). PERM for time layers.
__global__ __launch_bounds__(512, 1)
void mfma_panel_acc(const bf16* __restrict__ A, int lda, int koff, int K,
                    const bf16* __restrict__ Bt, int ldb,
                    const float* __restrict__ bias,
                    float* __restrict__ C, int ldc,
                    int nrow, int mchunk, int perm) {
    __shared__ __align__(16) short lds_b[64 * 1024];   // 128 KB (max K=1024)
    int gx = gridDim.x;
    int nwg = gx * gridDim.y;
    int lin = blockIdx.y * gx + blockIdx.x;
    int q8 = nwg >> 3, r8 = nwg & 7;
    int xcd = lin & 7, idx = lin >> 3;
    int wsw = (xcd < r8 ? xcd * (q8 + 1) : r8 * (q8 + 1) + (xcd - r8) * q8) + idx;
    int bx = wsw % gx, by = wsw / gx;
    int n0 = bx * 64, m0 = by * mchunk;

    int tid = threadIdx.x;
    int wave = tid >> 6, lane = tid & 63;
    int quad = lane >> 4, l16 = lane & 15;

    // stage B panel: 64 * (K/8) granules; granule gi: c = gi>>6, n = gi&63
    const short* Bp = (const short*)Bt;
    int ng = (K >> 3) * 64;
    for (int gi = tid; gi < ng; gi += 512) {
        int n = gi & 63, c = gi >> 6;
        async16(Bp + (size_t)(n0 + n) * ldb + koff + c * 8, &lds_b[gi * 8]);
    }
    float bs4[4];
    #pragma unroll
    for (int t = 0; t < 4; ++t)
        bs4[t] = bias ? bias[n0 + t * 16 + l16] : 0.f;
    __syncthreads();

    const short* Ap = (const short*)A;
    int nk = K >> 5;
    int nfrag = mchunk >> 4;
    for (int f = wave; f < nfrag; f += 8) {
        int mrow = m0 + f * 16 + l16;
        if (mrow >= nrow) mrow = nrow - 1;
        const short* ap = Ap + (size_t)mrow * lda + koff + quad * 8;
        f32x4 acc[4];
        #pragma unroll
        for (int nj = 0; nj < 4; ++nj) acc[nj] = {0.f, 0.f, 0.f, 0.f};
        short8 a = *(const short8*)ap;
        #pragma unroll 4
        for (int kt = 0; kt < nk; ++kt) {
            short8 anext = a;
            if (kt + 1 < nk) anext = *(const short8*)(ap + (kt + 1) * 32);
            const char* vb = (const char*)lds_b + ((kt * 4 + quad) * 64 + l16) * 16;
            __builtin_amdgcn_s_setprio(1);
            #pragma unroll
            for (int nj = 0; nj < 4; ++nj) {
                short8 b = *(const short8*)(vb + nj * 256);
                acc[nj] = __builtin_amdgcn_mfma_f32_16x16x32_bf16(a, b, acc[nj], 0, 0, 0);
            }
            __builtin_amdgcn_s_setprio(0);
            a = anext;
        }
        #pragma unroll
        for (int e = 0; e < 4; ++e) {
            int row = m0 + f * 16 + quad * 4 + e;
            if (row >= nrow) continue;
            int orow = row;
            if (perm) {
                int t = row & 15; int rs = row >> 4; int s = rs % SSQ; int b = rs / SSQ;
                orow = (b * TT + t) * SSQ + s;
            }
            float* cr = C + (size_t)orow * ldc + n0;
            #pragma unroll
            for (int nj = 0; nj < 4; ++nj)
                cr[nj * 16 + l16] += acc[nj][e] + bs4[nj];
        }
    }
}

// ---------------- V transpose for PV MFMA: vt[bt*8+kh][64][SKP] bf16 ----------------
__global__ void vtrans_kernel(const bf16* __restrict__ qkv, bf16* __restrict__ vt) {
    int bkh = blockIdx.x;          // bt*8 + kh
    int kc = blockIdx.y;           // key chunk of 32
    int bt = bkh >> 3, kh = bkh & 7;
    int tid = threadIdx.x;
    #pragma unroll
    for (int i = 0; i < 8; ++i) {
        int idx = tid + 256 * i;   // 0..2047
        int kl = idx >> 6;         // key local
        int d = idx & 63;
        int key = kc * 32 + kl;
        float v = 0.f;
        if (key < SSQ)
            v = __bfloat162float(qkv[((size_t)(bt * SSQ + key)) * 2048 + 1536 + kh * 64 + d]);
        vt[((size_t)bkh * 64 + d) * SKP + key] = __float2bfloat16(v);
    }
}

// ---------------- space attention: S^T in registers, K staged in LDS ----------------
__global__ __launch_bounds__(256)
void space_attn_kernel(const bf16* __restrict__ qkv, const bf16* __restrict__ vt,
                       bf16* __restrict__ ob) {
    __shared__ __align__(16) short kls[272 * 8 * 8];   // granule (key,c): K[key][8*(c^(key&7))..+8)
    int qt = blockIdx.x, qh = blockIdx.y, bt = blockIdx.z;
    int kh = qh >> 1;
    int tid = threadIdx.x, wave = tid >> 6, lane = tid & 63;
    int quad = lane >> 4, l16 = lane & 15;
    int q0w = qt * 64 + wave * 16;
    int q = q0w + l16;
    int qc = q > 256 ? 256 : q;
    const short* qbase = (const short*)qkv + (size_t)bt * SSQ * 2048;

    const short* kgbase = qbase + 1024 + kh * 64;
    #pragma unroll
    for (int it = 0; it < 9; ++it) {
        int u = it * 4 + wave;
        if (u < 34) {
            int g = u * 64 + lane;
            int key = g >> 3, ch = g & 7;
            int srck = key < SSQ ? key : 256;
            async16(kgbase + (size_t)srck * 2048 + (ch ^ (key & 7)) * 8,
                    &kls[u * 512]);
        }
    }

    const short* qp = qbase + (size_t)qc * 2048 + qh * 64;
    short8 bq0 = *(const short8*)(qp + quad * 8);
    short8 bq1 = *(const short8*)(qp + 32 + quad * 8);
    __syncthreads();   // drains vmcnt: K staged

    f32x4 zero4 = {0.f, 0.f, 0.f, 0.f};
    f32x4 sc[18];
    float sum = 0.f;
    int c0 = quad ^ (l16 & 7);   // key&7 == l16&7 since kt*16 % 8 == 0
    #pragma unroll
    for (int kt = 0; kt < 17; ++kt) {
        int key = kt * 16 + l16;
        short8 ak0 = *(const short8*)&kls[(key * 8 + c0) * 8];
        short8 ak1 = *(const short8*)&kls[(key * 8 + (c0 ^ 4)) * 8];
        f32x4 cc = zero4;
        cc = __builtin_amdgcn_mfma_f32_16x16x32_bf16(ak0, bq0, cc, 0, 0, 0);
        cc = __builtin_amdgcn_mfma_f32_16x16x32_bf16(ak1, bq1, cc, 0, 0, 0);
        #pragma unroll
        for (int e = 0; e < 4; ++e) {
            float x = cc[e] * 0.0025f;           // s/50, s = dot/8
            float x2 = x * x;
            float v = cc[e] * 0.125f * (1.f + x2 * (-0.3333333333f + x2 * 0.1333333333f));
            float p = __expf(v);                 // v in [-8.1, 8.1]: no overflow
            if (kt == 16) {
                bool valid = (e == 0) && (quad == 0) && (q == 256);
                p = valid ? p : 0.f;
            }
            cc[e] = p;
            sum += p;
        }
        sc[kt] = cc;
    }
    #pragma unroll
    for (int e = 0; e < 4; ++e) sc[17][e] = 0.f;
    sum += __shfl_xor(sum, 16);
    sum += __shfl_xor(sum, 32);
    float inv = __builtin_amdgcn_rcpf(sum);
    f32x4 inv4;
    #pragma unroll
    for (int e = 0; e < 4; ++e) inv4[e] = __shfl(inv, quad * 4 + e);

    f32x4 oacc[4];
    #pragma unroll
    for (int nt = 0; nt < 4; ++nt) oacc[nt] = zero4;
    const short* vbp = (const short*)vt + ((size_t)(bt * 8 + kh) * 64 + l16) * SKP;
    #pragma unroll
    for (int c8 = 0; c8 < 9; ++c8) {
        short8 pb;
        #pragma unroll
        for (int j = 0; j < 8; ++j) {
            int src_lane = ((quad & 1) * 2 + (j >> 2)) * 16 + l16;
            float v0 = __shfl(sc[2 * c8][j & 3], src_lane);
            float v1 = __shfl(sc[2 * c8 + 1][j & 3], src_lane);
            pb[j] = f2bfs(quad < 2 ? v0 : v1);
        }
        #pragma unroll
        for (int nt = 0; nt < 4; ++nt) {
            short8 av = *(const short8*)(vbp + (size_t)(nt * 16) * SKP + c8 * 32 + quad * 8);
            oacc[nt] = __builtin_amdgcn_mfma_f32_16x16x32_bf16(pb, av, oacc[nt], 0, 0, 0);
        }
    }

    #pragma unroll
    for (int e = 0; e < 4; ++e) {
        int qq = q0w + quad * 4 + e;
        if (qq <= 256) {
            bf16* op = ob + ((size_t)(bt * SSQ + qq)) * 1024 + qh * 64 + l16;
            float s = inv4[e];
            op[0]  = __float2bfloat16(oacc[0][e] * s);
            op[16] = __float2bfloat16(oacc[1][e] * s);
            op[32] = __float2bfloat16(oacc[2][e] * s);
            op[48] = __float2bfloat16(oacc[3][e] * s);
        }
    }
}

// ---------------- time attention (n=16, causal): MFMA, one wave per (bs, qh) --------
// Block = (bs, 4 heads). K staged via global_load_lds with c^(key&7) swizzle;
// V reg-staged TRANSPOSED into LDS [d][key] pad-24 (2-way banks only); Q direct.
// Per wave: 2 MFMA S^T (lane: query=l16, key=quad*4+e), poly-tanh + no-max softmax,
// 8 shuffles build P as A-fragment (keys>=16 zero), 4 MFMA PV, scale at store.
__global__ __launch_bounds__(256)
void time_attn_kernel(const bf16* __restrict__ qkv, bf16* __restrict__ ob) {
    __shared__ __align__(16) short kls[2 * 16 * 64];    // [khl][key][8 gran], XOR-swizzled
    __shared__ __align__(16) short vls[2 * 64 * 24];    // [khl][d][key pad 24]
    int bs = blockIdx.x, qg = blockIdx.y;
    int tid = threadIdx.x, wave = tid >> 6, lane = tid & 63;
    int quad = lane >> 4, l16 = lane & 15;
    int qh = qg * 4 + wave;
    int khl_w = wave >> 1;
    size_t rowbase = (size_t)bs * 16;
    const short* qbase = (const short*)qkv;

    // stage K (async, swizzled) + V (reg -> transposed LDS): thread -> (khl,key,c)
    {
        int c = tid & 7, key = (tid >> 3) & 15, khl = tid >> 7;
        const short* ksrc = qbase + (rowbase + key) * 2048 + 1024 + (qg * 2 + khl) * 64
                            + (c ^ (key & 7)) * 8;
        async16(ksrc, &kls[((khl * 16 + key) * 8 + c) * 8]);
        short8 vv = *(const short8*)(qbase + (rowbase + key) * 2048 + 1536
                                     + (qg * 2 + khl) * 64 + c * 8);
        #pragma unroll
        for (int dd = 0; dd < 8; ++dd)
            vls[(khl * 64 + c * 8 + dd) * 24 + key] = vv[dd];
    }
    const short* qp = qbase + (rowbase + l16) * 2048 + qh * 64;
    short8 bq0 = *(const short8*)(qp + quad * 8);
    short8 bq1 = *(const short8*)(qp + 32 + quad * 8);
    __syncthreads();

    int c0 = quad ^ (l16 & 7);
    const short* kw = &kls[(khl_w * 16 + l16) * 64];
    short8 ak0 = *(const short8*)(kw + c0 * 8);
    short8 ak1 = *(const short8*)(kw + (c0 ^ 4) * 8);
    f32x4 cc = {0.f, 0.f, 0.f, 0.f};
    cc = __builtin_amdgcn_mfma_f32_16x16x32_bf16(ak0, bq0, cc, 0, 0, 0);
    cc = __builtin_amdgcn_mfma_f32_16x16x32_bf16(ak1, bq1, cc, 0, 0, 0);
    float sum = 0.f;
    #pragma unroll
    for (int e = 0; e < 4; ++e) {
        float s = cc[e] * 0.125f;
        float x = s * 0.02f, x2 = x * x;
        float v = s * (1.f + x2 * (-0.3333333333f + x2 * 0.1333333333f));
        float p = ((quad * 4 + e) > l16) ? 0.f : __expf(v);
        cc[e] = p;
        sum += p;
    }
    sum += __shfl_xor(sum, 16);
    sum += __shfl_xor(sum, 32);
    float inv = __builtin_amdgcn_rcpf(sum);
    f32x4 inv4;
    #pragma unroll
    for (int e = 0; e < 4; ++e) inv4[e] = __shfl(inv, quad * 4 + e);

    // P as A fragment: pa[jj] = P[query=l16][key=quad*8+jj]; keys>=16 -> 0
    short8 pa;
    #pragma unroll
    for (int jj = 0; jj < 8; ++jj) {
        int key = quad * 8 + jj;
        int src = ((key >> 2) & 3) * 16 + l16;
        float v = __shfl(cc[jj & 3], src);
        pa[jj] = f2bfs(quad < 2 ? v : 0.f);
    }
    const short* vw = &vls[khl_w * 64 * 24];
    short8 zero8 = {0, 0, 0, 0, 0, 0, 0, 0};
    f32x4 oacc[4];
    #pragma unroll
    for (int nt = 0; nt < 4; ++nt) {
        short8 av = zero8;
        if (quad < 2)
            av = *(const short8*)(vw + (nt * 16 + l16) * 24 + quad * 8);
        f32x4 z = {0.f, 0.f, 0.f, 0.f};
        oacc[nt] = __builtin_amdgcn_mfma_f32_16x16x32_bf16(pa, av, z, 0, 0, 0);
    }
    #pragma unroll
    for (int e = 0; e < 4; ++e) {
        int q = quad * 4 + e;
        bf16* op = ob + (rowbase + q) * 1024 + qh * 64 + l16;
        float s = inv4[e];
        op[0]  = __float2bfloat16(oacc[0][e] * s);
        op[16] = __float2bfloat16(oacc[1][e] * s);
        op[32] = __float2bfloat16(oacc[2][e] * s);
        op[48] = __float2bfloat16(oacc[3][e] * s);
    }
}

// ---------------- host-side launch ----------------
extern "C" void kernel_launch(void* const* d_in, const int* in_sizes, int n_in,
                              void* d_out, int out_size, void* d_ws, size_t ws_size,
                              hipStream_t stream) {
    const float* tokens      = (const float*)d_in[0];
    const float* attn_norm_w = (const float*)d_in[1];
    const float* Wq          = (const float*)d_in[2];
    const float* Wk          = (const float*)d_in[3];
    const float* Wv          = (const float*)d_in[4];
    const float* q_gamma     = (const float*)d_in[5];
    const float* k_gamma     = (const float*)d_in[6];
    const float* Wo          = (const float*)d_in[7];
    const float* ff_norm_w   = (const float*)d_in[8];
    const float* W_in        = (const float*)d_in[9];
    const float* b_in        = (const float*)d_in[10];
    const float* W_out       = (const float*)d_in[11];
    const float* b_out       = (const float*)d_in[12];
    const float* final_w     = (const float*)d_in[13];

    float* x = (float*)d_out;
    char* ws = (char*)d_ws;

    bf16* wtqkv = (bf16*)ws;                     // [2048][512]
    bf16* wto   = wtqkv + 2048 * 512;            // [512][1024]
    bf16* wtin  = wto   + 512 * 1024;            // [2816][512] interleaved
    bf16* wtout = wtin  + 2816 * 512;            // [512][1408]
    size_t off = (size_t)(2048*512 + 512*1024 + 2816*512 + 512*1408) * 2;
    bf16* h = (bf16*)(ws + off);                 // [N][512]
    off += (size_t)NROWS * 512 * 2;
    char* region = ws + off;
    bf16* qkv = (bf16*)region;                               // [N][2048]
    bf16* glu = (bf16*)region;                               // [N][1408] (FF alias)
    bf16* vt  = (bf16*)(region + (size_t)NROWS * 2048 * 2);  // [256][64][288]
    bf16* ob  = (bf16*)(region + (size_t)NROWS * 2048 * 2 + (size_t)256*64*SKP*2);  // [N][1024]

    hipMemcpyAsync(x, tokens, (size_t)NROWS * 512 * 4, hipMemcpyDeviceToDevice, stream);

    for (int l = 0; l < 8; ++l) {
        int is_time = ((l + 1) % 4 == 0) ? 1 : 0;
        wtrans_layer<<<3648, 256, 0, stream>>>(
            Wq + (size_t)l * 512 * 1024, Wk + (size_t)l * 512 * 512,
            Wv + (size_t)l * 512 * 512, Wo + (size_t)l * 1024 * 512,
            W_in + (size_t)l * 512 * DI2, W_out + (size_t)l * DII * 512,
            wtqkv, wto, wtin, wtout);

        // ---- attention block ----
        rms_kernel<1><<<2056, 256, 0, stream>>>(x, attn_norm_w + (size_t)l * 512, h, is_time);
        mfma_gemm_panel<1><<<dim3(16, 16), 512, 0, stream>>>(
            h, 512, wtqkv, 512, nullptr, qkv, 2048, NROWS, 528,
            q_gamma + (size_t)l * 1024, k_gamma + (size_t)l * 512, is_time);
        if (is_time) {
            time_attn_kernel<<<dim3(514, 4), 256, 0, stream>>>(qkv, ob);
        } else {
            vtrans_kernel<<<dim3(256, 9), 256, 0, stream>>>(qkv, vt);
            space_attn_kernel<<<dim3(5, 16, 32), 256, 0, stream>>>(qkv, vt, ob);
        }
        mfma_panel_acc<<<dim3(8, 31), 512, 0, stream>>>(
            ob, 1024, 0, 1024, wto, 1024, nullptr, x, 512, NROWS, 272, is_time);

        // ---- feed-forward block ----
        rms_kernel<1><<<2056, 256, 0, stream>>>(x, ff_norm_w + (size_t)l * 512, h, 0);
        mfma_gemm_panel<2><<<dim3(22, 11), 512, 0, stream>>>(
            h, 512, wtin, 512, b_in + (size_t)l * DI2, glu, GLULD, NROWS, 768,
            nullptr, nullptr, 0);
        mfma_panel_acc<<<dim3(8, 31), 512, 0, stream>>>(
            glu, GLULD, 0, 1024, wtout, GLULD, b_out + (size_t)l * 512, x, 512,
            NROWS, 272, 0);
        mfma_panel_acc<<<dim3(8, 31), 512, 0, stream>>>(
            glu, GLULD, 1024, 384, wtout, GLULD, nullptr, x, 512,
            NROWS, 272, 0);
    }

    rms_kernel<0><<<2056, 256, 0, stream>>>(x, final_w, x, 0);
}

// Round 9
// 1958.245 us; speedup vs baseline: 1.0937x; 1.0937x over previous
//
#include <hip/hip_runtime.h>
#include <hip/hip_bf16.h>
#include <math.h>

typedef __attribute__((ext_vector_type(8))) short short8;
typedef __attribute__((ext_vector_type(4))) float f32x4;
typedef __hip_bfloat16 bf16;

#define BB 2
#define TT 16
#define SSQ 257
#define DIMD 512
#define NROWS 8224          // B*T*S
#define DII 1365
#define DI2 2730
#define FNPAD 2816          // ff_in N padded (22*128), block-16 interleaved a/g
#define GLULD 1408          // glu row stride / ff_out K (44*32)
#define SKP 288             // legacy pad (workspace layout only)
#define SKP2 320            // V LDS pad: 40 chunks of 8 keys (d-stride == 0 mod 8 groups)
#define EPSR 1.1920929e-07f

__device__ __forceinline__ void async16(const void* g, const void* l) {
    __builtin_amdgcn_global_load_lds(
        (const __attribute__((address_space(1))) void*)g,
        (__attribute__((address_space(3))) void*)l, 16, 0, 0);
}

__device__ __forceinline__ short f2bfs(float x) {
    bf16 h = __float2bfloat16(x);
    return *reinterpret_cast<short*>(&h);
}

// fast exact-gelu: a * g * Phi(g), erf via A&S 7.1.26 (abs err 1.5e-7)
__device__ __forceinline__ float glu_fast(float a, float g) {
    float x = g * 0.70710678118654752f;
    float ax = fabsf(x);
    float t = __builtin_amdgcn_rcpf(__builtin_fmaf(0.3275911f, ax, 1.f));
    float p = t * (0.254829592f + t * (-0.284496736f + t * (1.421413741f
              + t * (-1.453152027f + t * 1.061405429f))));
    float erfv = 1.f - p * __expf(-ax * ax);
    erfv = (x < 0.f) ? -erfv : erfv;
    return a * 0.5f * g * (1.f + erfv);
}

// ---------------- batched per-layer weight transpose fp32->bf16 ----------------
// win interleave: a_j -> col (j>>4)*32 + (j&15); g_j -> col (j>>4)*32 + 16 + (j&15)
__global__ void wtrans_layer(const float* __restrict__ wq, const float* __restrict__ wk,
                             const float* __restrict__ wv, const float* __restrict__ wo,
                             const float* __restrict__ win, const float* __restrict__ wout,
                             bf16* __restrict__ dqkv, bf16* __restrict__ dwo,
                             bf16* __restrict__ dwin, bf16* __restrict__ dwout) {
    __shared__ float tile[32][33];
    int bid = blockIdx.x;
    const float* src; bf16* dst; int K, M, Kpad, interleave = 0, local;
    if (bid < 512)       { src = wq;   dst = dqkv;            K = 512;  M = 1024; Kpad = 512;  local = bid; }
    else if (bid < 768)  { src = wk;   dst = dqkv + 1024*512; K = 512;  M = 512;  Kpad = 512;  local = bid - 512; }
    else if (bid < 1024) { src = wv;   dst = dqkv + 1536*512; K = 512;  M = 512;  Kpad = 512;  local = bid - 768; }
    else if (bid < 1536) { src = wo;   dst = dwo;             K = 1024; M = 512;  Kpad = 1024; local = bid - 1024; }
    else if (bid < 2944) { src = win;  dst = dwin;            K = 512;  M = 2730; Kpad = 512;  local = bid - 1536; interleave = 1; }
    else                 { src = wout; dst = dwout;           K = 1365; M = 512;  Kpad = 1408; local = bid - 2944; }
    int tilesx = Kpad >> 5;
    int k0 = (local % tilesx) * 32, m0 = (local / tilesx) * 32;
    int tx = threadIdx.x & 31, ty = threadIdx.x >> 5;
    #pragma unroll
    for (int i = 0; i < 4; ++i) {
        int k = k0 + ty + 8 * i, m = m0 + tx;
        tile[ty + 8 * i][tx] = (k < K && m < M) ? src[(size_t)k * M + m] : 0.f;
    }
    __syncthreads();
    #pragma unroll
    for (int i = 0; i < 4; ++i) {
        int n = m0 + ty + 8 * i, k = k0 + tx;
        int nd = n;
        if (interleave) {
            if (n < DII)        nd = ((n >> 4) << 5) + (n & 15);
            else if (n < DI2) { int m = n - DII; nd = ((m >> 4) << 5) + 16 + (m & 15); }
            else              { int q = n - DI2; int j = DII + (q >> 1);
                                nd = ((j >> 4) << 5) + ((q & 1) << 4) + (j & 15); }
        }
        dst[(size_t)nd * Kpad + k] = __float2bfloat16(tile[tx][ty + 8 * i]);
    }
}

// ---------------- RMSNorm: one wave per row, float4 loads, shuffle reduce ----------------
template<int BF16OUT>
__global__ __launch_bounds__(256)
void rms_kernel(const float* __restrict__ x, const float* __restrict__ w,
                void* __restrict__ out, int perm) {
    int wave = threadIdx.x >> 6, lane = threadIdx.x & 63;
    int r = blockIdx.x * 4 + wave;
    int src = r;
    if (perm) {
        int t = r & 15; int rs = r >> 4; int s = rs % SSQ; int b = rs / SSQ;
        src = (b * TT + t) * SSQ + s;
    }
    const float4* xr = (const float4*)(x + (size_t)src * DIMD) + lane * 2;
    float4 a = xr[0], c = xr[1];
    float ss = a.x*a.x + a.y*a.y + a.z*a.z + a.w*a.w
             + c.x*c.x + c.y*c.y + c.z*c.z + c.w*c.w;
    ss += __shfl_xor(ss, 1);  ss += __shfl_xor(ss, 2);  ss += __shfl_xor(ss, 4);
    ss += __shfl_xor(ss, 8);  ss += __shfl_xor(ss, 16); ss += __shfl_xor(ss, 32);
    float sc = rsqrtf(ss * (1.f / DIMD) + EPSR);
    const float4* wr = (const float4*)w + lane * 2;
    float4 wa = wr[0], wb = wr[1];
    if (BF16OUT) {
        short8 v;
        v[0] = f2bfs(a.x * sc * wa.x); v[1] = f2bfs(a.y * sc * wa.y);
        v[2] = f2bfs(a.z * sc * wa.z); v[3] = f2bfs(a.w * sc * wa.w);
        v[4] = f2bfs(c.x * sc * wb.x); v[5] = f2bfs(c.y * sc * wb.y);
        v[6] = f2bfs(c.z * sc * wb.z); v[7] = f2bfs(c.w * sc * wb.w);
        *(short8*)((bf16*)out + (size_t)r * DIMD + lane * 8) = v;
    } else {
        float4* o = (float4*)((float*)out + (size_t)r * DIMD) + lane * 2;
        float4 o0 = {a.x * sc * wa.x, a.y * sc * wa.y, a.z * sc * wa.z, a.w * sc * wa.w};
        float4 o1 = {c.x * sc * wb.x, c.y * sc * wb.y, c.z * sc * wb.z, c.w * sc * wb.w};
        o[0] = o0; o[1] = o1;
    }
}

// ---------------- panel MFMA GEMM: B-panel resident in LDS, barrier-free loop --------
// K=512: full 128-col B panel = 128KB = one LDS, loaded once (transposed granule
// layout). No barriers after: each of 8 waves streams its own m-frags, A direct
// from global (L2/L3-hot, XCD-swizzled), 1-deep A prefetch, 8 MFMA per K-step.
// EPI: 1 = qkv + fused l2norm/gamma/rotary; 2 = glu (block-16 interleaved a/g).
template<int EPI>
__global__ __launch_bounds__(512, 1)
void mfma_gemm_panel(const bf16* __restrict__ A, int lda,
                     const bf16* __restrict__ Bt, int ldb,
                     const float* __restrict__ bias,
                     void* __restrict__ C, int ldc,
                     int nrow, int mchunk,
                     const float* __restrict__ qg, const float* __restrict__ kg,
                     int rotary) {
    __shared__ __align__(16) short lds_b[128 * 512];   // 128 KB
    // T1: bijective XCD-aware remap (m204)
    int gx = gridDim.x;
    int nwg = gx * gridDim.y;
    int lin = blockIdx.y * gx + blockIdx.x;
    int q8 = nwg >> 3, r8 = nwg & 7;
    int xcd = lin & 7, idx = lin >> 3;
    int wsw = (xcd < r8 ? xcd * (q8 + 1) : r8 * (q8 + 1) + (xcd - r8) * q8) + idx;
    int bx = wsw % gx, by = wsw / gx;
    int n0 = bx * 128, m0 = by * mchunk;

    int tid = threadIdx.x;
    int wave = tid >> 6, lane = tid & 63;
    int quad = lane >> 4, l16 = lane & 15;

    // stage B panel: 8192 granules of 16B; granule gi: c = gi>>7, n = gi&127
    const short* Bp = (const short*)Bt;
    #pragma unroll
    for (int j = 0; j < 16; ++j) {
        int gi = tid + 512 * j;
        int n = gi & 127, c = gi >> 7;
        async16(Bp + (size_t)(n0 + n) * ldb + c * 8, &lds_b[gi * 8]);
    }
    const short* Ap = (const short*)A;

    // hoisted epilogue constants
    float gl[2][4];
    float c0r[4], s0r[4], c1r[4], s1r[4];
    bool isqk = false;
    float ba[4], bg[4];
    if constexpr (EPI == 1) {
        int headb = n0 >> 6;
        isqk = headb < 24;
        if (isqk) {
            #pragma unroll
            for (int hh = 0; hh < 2; ++hh) {
                int head = headb + hh;
                const float* g = head < 16 ? qg + head * 64 : kg + (head - 16) * 64;
                gl[hh][0] = (g[l16] + 1.f) * 8.f;
                gl[hh][1] = (g[16 + l16] + 1.f) * 8.f;
                gl[hh][2] = (g[32 + l16] + 1.f) * 8.f;
                gl[hh][3] = (g[48 + l16] + 1.f) * 8.f;
            }
        }
        if (rotary) {
            float inv0 = __expf(-(float)l16 * 0.28782313662425572f);        // ln(1e4)/32
            float inv1 = __expf(-(float)(l16 + 16) * 0.28782313662425572f);
            #pragma unroll
            for (int e = 0; e < 4; ++e) {
                float t = (float)(quad * 4 + e);
                c0r[e] = __cosf(t * inv0); s0r[e] = __sinf(t * inv0);
                c1r[e] = __cosf(t * inv1); s1r[e] = __sinf(t * inv1);
            }
        }
    } else {
        int jb = n0 >> 1;
        #pragma unroll
        for (int t = 0; t < 4; ++t) {
            int j = jb + t * 16 + l16;
            ba[t] = (j < DII) ? bias[j] : 0.f;
            bg[t] = (j < DII) ? bias[DII + j] : 0.f;
        }
    }
    __syncthreads();   // B panel resident (drains vmcnt before barrier)

    int base_b = (quad * 128 + l16) * 16;   // byte addr of granule (c=quad, n=l16)
    int nfrag = mchunk >> 4;
    for (int f = wave; f < nfrag; f += 8) {
        int mrow = m0 + f * 16 + l16;
        if (mrow >= nrow) mrow = nrow - 1;          // clamp; C-write guarded below
        const short* ap = Ap + (size_t)mrow * lda + quad * 8;
        f32x4 acc[8];
        #pragma unroll
        for (int nj = 0; nj < 8; ++nj) acc[nj] = {0.f, 0.f, 0.f, 0.f};
        short8 a = *(const short8*)ap;
        short8 anext = a;
        #pragma unroll
        for (int kt = 0; kt < 16; ++kt) {
            if (kt < 15) anext = *(const short8*)(ap + (kt + 1) * 32);
            const char* vb = (const char*)lds_b + base_b + kt * 8192;
            __builtin_amdgcn_s_setprio(1);
            #pragma unroll
            for (int nj = 0; nj < 8; ++nj) {
                short8 b = *(const short8*)(vb + nj * 256);
                acc[nj] = __builtin_amdgcn_mfma_f32_16x16x32_bf16(a, b, acc[nj], 0, 0, 0);
            }
            __builtin_amdgcn_s_setprio(0);
            a = anext;
        }
        if constexpr (EPI == 1) {
            #pragma unroll
            for (int hh = 0; hh < 2; ++hh) {
                #pragma unroll
                for (int e = 0; e < 4; ++e) {
                    int row = m0 + f * 16 + quad * 4 + e;
                    float v0 = acc[hh * 4 + 0][e], v1 = acc[hh * 4 + 1][e];
                    float v2 = acc[hh * 4 + 2][e], v3 = acc[hh * 4 + 3][e];
                    if (isqk) {
                        float ss = v0 * v0 + v1 * v1 + v2 * v2 + v3 * v3;
                        ss += __shfl_xor(ss, 1); ss += __shfl_xor(ss, 2);
                        ss += __shfl_xor(ss, 4); ss += __shfl_xor(ss, 8);
                        float invn = 1.f / fmaxf(sqrtf(ss), 1e-12f);
                        v0 *= invn * gl[hh][0]; v1 *= invn * gl[hh][1];
                        v2 *= invn * gl[hh][2]; v3 *= invn * gl[hh][3];
                        if (rotary) {
                            float n0v = v0 * c0r[e] - v2 * s0r[e];
                            float n1v = v1 * c1r[e] - v3 * s1r[e];
                            float n2v = v2 * c0r[e] + v0 * s0r[e];
                            float n3v = v3 * c1r[e] + v1 * s1r[e];
                            v0 = n0v; v1 = n1v; v2 = n2v; v3 = n3v;
                        }
                    }
                    if (row < nrow) {
                        bf16* p = (bf16*)C + (size_t)row * ldc + n0 + hh * 64 + l16;
                        p[0]  = __float2bfloat16(v0);
                        p[16] = __float2bfloat16(v1);
                        p[32] = __float2bfloat16(v2);
                        p[48] = __float2bfloat16(v3);
                    }
                }
            }
        } else {
            int jb = n0 >> 1;
            #pragma unroll
            for (int e = 0; e < 4; ++e) {
                int row = m0 + f * 16 + quad * 4 + e;
                if (row < nrow) {
                    bf16* cr = (bf16*)C + (size_t)row * ldc;
                    #pragma unroll
                    for (int t = 0; t < 4; ++t)
                        cr[jb + t * 16 + l16] = __float2bfloat16(
                            glu_fast(acc[2 * t][e] + ba[t], acc[2 * t + 1][e] + bg[t]));
                }
            }
        }
    }
}

// ---------------- MFMA bf16 GEMM (small): C[nrow,M] = A @ Bt^T ----------------
// TM x 128 tile, BK=32, double-buffered, granule swizzle kc' = kc^((m>>1)&3).
// 4 waves. EPI 3 = fp32 accumulate (+= into C), optional PERM store.
// (restored round-5-measured config for wo / ff_out)
template<int EPI, int PERM, int TM>
__global__ __launch_bounds__(256)
void mfma_gemm(const bf16* __restrict__ A, int lda,
               const bf16* __restrict__ Bt, int ldb,
               const float* __restrict__ bias,
               void* __restrict__ C, int ldc, int Mstore,
               int nrow, int K) {
    constexpr int MI = TM / 32;
    constexpr int ALW = TM / 64;
    __shared__ __align__(16) short lds_a[2][TM * 32];
    __shared__ __align__(16) short lds_b[2][128 * 32];
    int tid = threadIdx.x;
    int wave = tid >> 6, lane = tid & 63;
    int quad = lane >> 4, l16 = lane & 15;
    int m0 = blockIdx.y * TM, n0 = blockIdx.x * 128;
    int wm = (wave & 1) * (TM / 2), wn = (wave >> 1) * 64;
    f32x4 zero4 = {0.f, 0.f, 0.f, 0.f};
    f32x4 acc[MI][4];
    #pragma unroll
    for (int i = 0; i < MI; ++i)
        #pragma unroll
        for (int j = 0; j < 4; ++j) acc[i][j] = zero4;

    const short* Ap = (const short*)A;
    const short* Bp = (const short*)Bt;
    auto aptr = [&](int g) {
        int m = g >> 2, kc = (g & 3) ^ ((g >> 3) & 3);
        int r = m0 + m; if (r >= nrow) r = nrow - 1;
        return Ap + (size_t)r * lda + kc * 8;
    };
    auto bptr = [&](int g) {
        int m = g >> 2, kc = (g & 3) ^ ((g >> 3) & 3);
        return Bp + (size_t)(n0 + m) * ldb + kc * 8;
    };
    const short* gA[ALW]; int aoff[ALW];
    #pragma unroll
    for (int j = 0; j < ALW; ++j) {
        gA[j] = aptr(wave * TM + j * 64 + lane);
        aoff[j] = (wave * TM + j * 64) * 8;
    }
    const short* gB0 = bptr(wave * 128 + lane);
    const short* gB1 = bptr(wave * 128 + 64 + lane);
    int boff0 = (wave * 128) * 8, boff1 = (wave * 128 + 64) * 8;

    auto stage = [&](int buf, int kt) {
        int ko = kt * 32;
        #pragma unroll
        for (int j = 0; j < ALW; ++j)
            async16(gA[j] + ko, &lds_a[buf][aoff[j]]);
        async16(gB0 + ko, &lds_b[buf][boff0]);
        async16(gB1 + ko, &lds_b[buf][boff1]);
    };

    int nk = K >> 5;
    stage(0, 0);
    for (int kt = 0; kt < nk; ++kt) {
        int buf = kt & 1;
        __syncthreads();
        if (kt + 1 < nk) stage(buf ^ 1, kt + 1);
        short8 af[MI], bfr[4];
        #pragma unroll
        for (int mi = 0; mi < MI; ++mi) {
            int m = wm + mi * 16 + l16;
            af[mi] = *(const short8*)&lds_a[buf][(m * 4 + (quad ^ ((m >> 1) & 3))) * 8];
        }
        #pragma unroll
        for (int nj = 0; nj < 4; ++nj) {
            int n = wn + nj * 16 + l16;
            bfr[nj] = *(const short8*)&lds_b[buf][(n * 4 + (quad ^ ((n >> 1) & 3))) * 8];
        }
        #pragma unroll
        for (int mi = 0; mi < MI; ++mi)
            #pragma unroll
            for (int nj = 0; nj < 4; ++nj)
                acc[mi][nj] = __builtin_amdgcn_mfma_f32_16x16x32_bf16(
                    af[mi], bfr[nj], acc[mi][nj], 0, 0, 0);
    }

    #pragma unroll
    for (int mi = 0; mi < MI; ++mi) {
        #pragma unroll
        for (int e = 0; e < 4; ++e) {
            int row = m0 + wm + mi * 16 + quad * 4 + e;
            if (row >= nrow) continue;
            int orow = row;
            if (PERM) {
                int t = row & 15; int rs = row >> 4; int s = rs % SSQ; int b = rs / SSQ;
                orow = (b * TT + t) * SSQ + s;
            }
            #pragma unroll
            for (int nj = 0; nj < 4; ++nj) {
                int col = n0 + wn + nj * 16 + l16;
                if (col >= Mstore) continue;
                float v = acc[mi][nj][e];
                if (bias) v += bias[col];
                ((float*)C)[(size_t)orow * ldc + col] += v;
            }
        }
    }
}

// ---------------- space attention: fused per-(bt,kh) block, K+V^T in LDS ----------------
// One 512-thread block per (bt,kh): K staged once (XOR-granule layout, as proven),
// V staged once reg->LDS TRANSPOSED as granules vls[d][kc^(d&7)] (16B = 8 keys),
// SKP2=320 chunks-of-8 so PV ds_read_b128 hits 8 lanes per 16B bank group
// (conflict-free). Then barrier-free: 8 waves stream 34 frags (17 qt x 2 qh),
// each the previously-verified QK^T / no-max-softmax / PV choreography.
// Eliminates the 10x K re-stage + 1.5GB/dispatch L2 V-traffic (was 51us, L2-bound).
__global__ __launch_bounds__(512)
void space_attn_kernel(const bf16* __restrict__ qkv, bf16* __restrict__ ob) {
    __shared__ __align__(16) short kls[272 * 8 * 8];   // 68KB: granule (key,c) = K[key][8*(c^(key&7))..]
    __shared__ __align__(16) short vls[64 * SKP2];     // 40KB: granule (d,kc^(d&7)) = V^T[d][kc*8..+8]
    int bt = blockIdx.x, kh = blockIdx.y;
    int tid = threadIdx.x, wave = tid >> 6, lane = tid & 63;
    int quad = lane >> 4, l16 = lane & 15;
    const short* qbase = (const short*)qkv + (size_t)bt * SSQ * 2048;
    const short* kgbase = qbase + 1024 + kh * 64;
    const short* vgbase = qbase + 1536 + kh * 64;

    // stage K: 272 keys x 8 chunks = 2176 granules of 16B (async, pre-swizzled src)
    #pragma unroll
    for (int u = 0; u < 5; ++u) {
        int g = u * 512 + tid;
        if (g < 2176) {
            int key = g >> 3, ch = g & 7;
            int srck = key < SSQ ? key : 256;
            async16(kgbase + (size_t)srck * 2048 + (ch ^ (key & 7)) * 8, &kls[g * 8]);
        }
    }
    // stage V transposed: read 16B of V[key][c*8..], scatter to vls[d][key]
    #pragma unroll
    for (int u = 0; u < 5; ++u) {
        int g = u * 512 + tid;
        if (g < 2176) {
            int key = g >> 3, c = g & 7;
            int srck = key < SSQ ? key : 256;
            short8 vv = *(const short8*)(vgbase + (size_t)srck * 2048 + c * 8);
            int kc = key >> 3, kl = key & 7;
            #pragma unroll
            for (int dd = 0; dd < 8; ++dd) {
                int d = c * 8 + dd;
                vls[(d * 40 + (kc ^ (d & 7))) * 8 + kl] = vv[dd];
            }
        }
    }
    // zero chunks kc=34,35 (keys 272..287, read by PV c8=8 but never written)
    if (tid < 128) {
        int d = tid >> 1, kc = 34 + (tid & 1);
        short8 z8 = {0, 0, 0, 0, 0, 0, 0, 0};
        *(short8*)&vls[(d * 40 + (kc ^ (d & 7))) * 8] = z8;
    }
    __syncthreads();   // drains vmcnt (K) + lgkm (V writes)

    f32x4 zero4 = {0.f, 0.f, 0.f, 0.f};
    int c0 = quad ^ (l16 & 7);
    int d7 = l16 & 7;          // (nt*16+l16)&7 == l16&7
    for (int f = wave; f < 34; f += 8) {
        int qh_l = (f >= 17) ? 1 : 0;
        int qt = f - qh_l * 17;
        int qh = kh * 2 + qh_l;
        int q = qt * 16 + l16;
        int qc = q > 256 ? 256 : q;
        const short* qp = qbase + (size_t)qc * 2048 + qh * 64;
        short8 bq0 = *(const short8*)(qp + quad * 8);
        short8 bq1 = *(const short8*)(qp + 32 + quad * 8);

        f32x4 sc[18];
        float sum = 0.f;
        #pragma unroll
        for (int kt = 0; kt < 17; ++kt) {
            int key = kt * 16 + l16;
            short8 ak0 = *(const short8*)&kls[(key * 8 + c0) * 8];
            short8 ak1 = *(const short8*)&kls[(key * 8 + (c0 ^ 4)) * 8];
            f32x4 cc = zero4;
            cc = __builtin_amdgcn_mfma_f32_16x16x32_bf16(ak0, bq0, cc, 0, 0, 0);
            cc = __builtin_amdgcn_mfma_f32_16x16x32_bf16(ak1, bq1, cc, 0, 0, 0);
            #pragma unroll
            for (int e = 0; e < 4; ++e) {
                float x = cc[e] * 0.0025f;           // s/50, s = dot/8
                float x2 = x * x;
                float v = cc[e] * 0.125f * (1.f + x2 * (-0.3333333333f + x2 * 0.1333333333f));
                float p = __expf(v);                 // v in [-8.1, 8.1]: no overflow
                if (kt == 16) {
                    bool valid = (e == 0) && (quad == 0) && (q == 256);
                    p = valid ? p : 0.f;
                }
                cc[e] = p;
                sum += p;
            }
            sc[kt] = cc;
        }
        #pragma unroll
        for (int e = 0; e < 4; ++e) sc[17][e] = 0.f;
        sum += __shfl_xor(sum, 16);
        sum += __shfl_xor(sum, 32);
        float inv = __builtin_amdgcn_rcpf(sum);
        f32x4 inv4;
        #pragma unroll
        for (int e = 0; e < 4; ++e) inv4[e] = __shfl(inv, quad * 4 + e);

        f32x4 oacc[4];
        #pragma unroll
        for (int nt = 0; nt < 4; ++nt) oacc[nt] = zero4;
        #pragma unroll
        for (int c8 = 0; c8 < 9; ++c8) {
            short8 pb;
            #pragma unroll
            for (int j = 0; j < 8; ++j) {
                int src_lane = ((quad & 1) * 2 + (j >> 2)) * 16 + l16;
                float v0 = __shfl(sc[2 * c8][j & 3], src_lane);
                float v1 = __shfl(sc[2 * c8 + 1][j & 3], src_lane);
                pb[j] = f2bfs(quad < 2 ? v0 : v1);
            }
            #pragma unroll
            for (int nt = 0; nt < 4; ++nt) {
                int d = nt * 16 + l16;
                int kc = (c8 * 4 + quad) ^ d7;
                short8 av = *(const short8*)&vls[(d * 40 + kc) * 8];
                oacc[nt] = __builtin_amdgcn_mfma_f32_16x16x32_bf16(pb, av, oacc[nt], 0, 0, 0);
            }
        }

        #pragma unroll
        for (int e = 0; e < 4; ++e) {
            int qq = qt * 16 + quad * 4 + e;
            if (qq <= 256) {
                bf16* op = ob + ((size_t)(bt * SSQ + qq)) * 1024 + qh * 64 + l16;
                float s = inv4[e];
                op[0]  = __float2bfloat16(oacc[0][e] * s);
                op[16] = __float2bfloat16(oacc[1][e] * s);
                op[32] = __float2bfloat16(oacc[2][e] * s);
                op[48] = __float2bfloat16(oacc[3][e] * s);
            }
        }
    }
}

// ---------------- time attention (n=16, causal): MFMA, one wave per (bs, qh) --------
__global__ __launch_bounds__(256)
void time_attn_kernel(const bf16* __restrict__ qkv, bf16* __restrict__ ob) {
    __shared__ __align__(16) short kls[2 * 16 * 64];    // [khl][key][8 gran], XOR-swizzled
    __shared__ __align__(16) short vls[2 * 64 * 24];    // [khl][d][key pad 24]
    int bs = blockIdx.x, qg = blockIdx.y;
    int tid = threadIdx.x, wave = tid >> 6, lane = tid & 63;
    int quad = lane >> 4, l16 = lane & 15;
    int qh = qg * 4 + wave;
    int khl_w = wave >> 1;
    size_t rowbase = (size_t)bs * 16;
    const short* qbase = (const short*)qkv;

    {
        int c = tid & 7, key = (tid >> 3) & 15, khl = tid >> 7;
        const short* ksrc = qbase + (rowbase + key) * 2048 + 1024 + (qg * 2 + khl) * 64
                            + (c ^ (key & 7)) * 8;
        async16(ksrc, &kls[((khl * 16 + key) * 8 + c) * 8]);
        short8 vv = *(const short8*)(qbase + (rowbase + key) * 2048 + 1536
                                     + (qg * 2 + khl) * 64 + c * 8);
        #pragma unroll
        for (int dd = 0; dd < 8; ++dd)
            vls[(khl * 64 + c * 8 + dd) * 24 + key] = vv[dd];
    }
    const short* qp = qbase + (rowbase + l16) * 2048 + qh * 64;
    short8 bq0 = *(const short8*)(qp + quad * 8);
    short8 bq1 = *(const short8*)(qp + 32 + quad * 8);
    __syncthreads();

    int c0 = quad ^ (l16 & 7);
    const short* kw = &kls[(khl_w * 16 + l16) * 64];
    short8 ak0 = *(const short8*)(kw + c0 * 8);
    short8 ak1 = *(const short8*)(kw + (c0 ^ 4) * 8);
    f32x4 cc = {0.f, 0.f, 0.f, 0.f};
    cc = __builtin_amdgcn_mfma_f32_16x16x32_bf16(ak0, bq0, cc, 0, 0, 0);
    cc = __builtin_amdgcn_mfma_f32_16x16x32_bf16(ak1, bq1, cc, 0, 0, 0);
    float sum = 0.f;
    #pragma unroll
    for (int e = 0; e < 4; ++e) {
        float s = cc[e] * 0.125f;
        float x = s * 0.02f, x2 = x * x;
        float v = s * (1.f + x2 * (-0.3333333333f + x2 * 0.1333333333f));
        float p = ((quad * 4 + e) > l16) ? 0.f : __expf(v);
        cc[e] = p;
        sum += p;
    }
    sum += __shfl_xor(sum, 16);
    sum += __shfl_xor(sum, 32);
    float inv = __builtin_amdgcn_rcpf(sum);
    f32x4 inv4;
    #pragma unroll
    for (int e = 0; e < 4; ++e) inv4[e] = __shfl(inv, quad * 4 + e);

    short8 pa;
    #pragma unroll
    for (int jj = 0; jj < 8; ++jj) {
        int key = quad * 8 + jj;
        int src = ((key >> 2) & 3) * 16 + l16;
        float v = __shfl(cc[jj & 3], src);
        pa[jj] = f2bfs(quad < 2 ? v : 0.f);
    }
    const short* vw = &vls[khl_w * 64 * 24];
    short8 zero8 = {0, 0, 0, 0, 0, 0, 0, 0};
    f32x4 oacc[4];
    #pragma unroll
    for (int nt = 0; nt < 4; ++nt) {
        short8 av = zero8;
        if (quad < 2)
            av = *(const short8*)(vw + (nt * 16 + l16) * 24 + quad * 8);
        f32x4 z = {0.f, 0.f, 0.f, 0.f};
        oacc[nt] = __builtin_amdgcn_mfma_f32_16x16x32_bf16(pa, av, z, 0, 0, 0);
    }
    #pragma unroll
    for (int e = 0; e < 4; ++e) {
        int q = quad * 4 + e;
        bf16* op = ob + (rowbase + q) * 1024 + qh * 64 + l16;
        float s = inv4[e];
        op[0]  = __float2bfloat16(oacc[0][e] * s);
        op[16] = __float2bfloat16(oacc[1][e] * s);
        op[32] = __float2bfloat16(oacc[2][e] * s);
        op[48] = __float2bfloat16(oacc[3][e] * s);
    }
}

// ---------------- host-side launch ----------------
extern "C" void kernel_launch(void* const* d_in, const int* in_sizes, int n_in,
                              void* d_out, int out_size, void* d_ws, size_t ws_size,
                              hipStream_t stream) {
    const float* tokens      = (const float*)d_in[0];
    const float* attn_norm_w = (const float*)d_in[1];
    const float* Wq          = (const float*)d_in[2];
    const float* Wk          = (const float*)d_in[3];
    const float* Wv          = (const float*)d_in[4];
    const float* q_gamma     = (const float*)d_in[5];
    const float* k_gamma     = (const float*)d_in[6];
    const float* Wo          = (const float*)d_in[7];
    const float* ff_norm_w   = (const float*)d_in[8];
    const float* W_in        = (const float*)d_in[9];
    const float* b_in        = (const float*)d_in[10];
    const float* W_out       = (const float*)d_in[11];
    const float* b_out       = (const float*)d_in[12];
    const float* final_w     = (const float*)d_in[13];

    float* x = (float*)d_out;
    char* ws = (char*)d_ws;

    bf16* wtqkv = (bf16*)ws;                     // [2048][512]
    bf16* wto   = wtqkv + 2048 * 512;            // [512][1024]
    bf16* wtin  = wto   + 512 * 1024;            // [2816][512] interleaved
    bf16* wtout = wtin  + 2816 * 512;            // [512][1408]
    size_t off = (size_t)(2048*512 + 512*1024 + 2816*512 + 512*1408) * 2;
    bf16* h = (bf16*)(ws + off);                 // [N][512]
    off += (size_t)NROWS * 512 * 2;
    char* region = ws + off;
    bf16* qkv = (bf16*)region;                               // [N][2048]
    bf16* glu = (bf16*)region;                               // [N][1408] (FF alias)
    bf16* ob  = (bf16*)(region + (size_t)NROWS * 2048 * 2 + (size_t)256*64*SKP*2);  // [N][1024]

    hipMemcpyAsync(x, tokens, (size_t)NROWS * 512 * 4, hipMemcpyDeviceToDevice, stream);

    for (int l = 0; l < 8; ++l) {
        int is_time = ((l + 1) % 4 == 0) ? 1 : 0;
        wtrans_layer<<<3648, 256, 0, stream>>>(
            Wq + (size_t)l * 512 * 1024, Wk + (size_t)l * 512 * 512,
            Wv + (size_t)l * 512 * 512, Wo + (size_t)l * 1024 * 512,
            W_in + (size_t)l * 512 * DI2, W_out + (size_t)l * DII * 512,
            wtqkv, wto, wtin, wtout);

        // ---- attention block ----
        rms_kernel<1><<<2056, 256, 0, stream>>>(x, attn_norm_w + (size_t)l * 512, h, is_time);
        mfma_gemm_panel<1><<<dim3(16, 16), 512, 0, stream>>>(
            h, 512, wtqkv, 512, nullptr, qkv, 2048, NROWS, 528,
            q_gamma + (size_t)l * 1024, k_gamma + (size_t)l * 512, is_time);
        if (is_time) {
            time_attn_kernel<<<dim3(514, 4), 256, 0, stream>>>(qkv, ob);
            mfma_gemm<3, 1, 64><<<dim3(4, 129), 256, 0, stream>>>(
                ob, 1024, wto, 1024, nullptr, x, 512, 512, NROWS, 1024);
        } else {
            space_attn_kernel<<<dim3(32, 8), 512, 0, stream>>>(qkv, ob);
            mfma_gemm<3, 0, 64><<<dim3(4, 129), 256, 0, stream>>>(
                ob, 1024, wto, 1024, nullptr, x, 512, 512, NROWS, 1024);
        }

        // ---- feed-forward block ----
        rms_kernel<1><<<2056, 256, 0, stream>>>(x, ff_norm_w + (size_t)l * 512, h, 0);
        mfma_gemm_panel<2><<<dim3(22, 11), 512, 0, stream>>>(
            h, 512, wtin, 512, b_in + (size_t)l * DI2, glu, GLULD, NROWS, 768,
            nullptr, nullptr, 0);
        mfma_gemm<3, 0, 64><<<dim3(4, 129), 256, 0, stream>>>(
            glu, GLULD, wtout, GLULD, b_out + (size_t)l * 512, x, 512, 512, NROWS, GLULD);
    }

    rms_kernel<0><<<2056, 256, 0, stream>>>(x, final_w, x, 0);
}

// Round 10
// 1864.632 us; speedup vs baseline: 1.1486x; 1.0502x over previous
//
#include <hip/hip_runtime.h>
#include <hip/hip_bf16.h>
#include <math.h>

typedef __attribute__((ext_vector_type(8))) short short8;
typedef __attribute__((ext_vector_type(4))) float f32x4;
typedef __hip_bfloat16 bf16;

#define BB 2
#define TT 16
#define SSQ 257
#define DIMD 512
#define NROWS 8224          // B*T*S
#define DII 1365
#define DI2 2730
#define FNPAD 2816          // ff_in N padded (22*128), block-16 interleaved a/g
#define GLULD 1408          // glu row stride / ff_out K (44*32)
#define SKP 288             // legacy pad (workspace layout only)
#define SKP2 320            // V LDS pad: 40 chunks of 8 keys
#define EPSR 1.1920929e-07f

__device__ __forceinline__ void async16(const void* g, const void* l) {
    __builtin_amdgcn_global_load_lds(
        (const __attribute__((address_space(1))) void*)g,
        (__attribute__((address_space(3))) void*)l, 16, 0, 0);
}

__device__ __forceinline__ short f2bfs(float x) {
    bf16 h = __float2bfloat16(x);
    return *reinterpret_cast<short*>(&h);
}

// fast exact-gelu: a * g * Phi(g), erf via A&S 7.1.26 (abs err 1.5e-7)
__device__ __forceinline__ float glu_fast(float a, float g) {
    float x = g * 0.70710678118654752f;
    float ax = fabsf(x);
    float t = __builtin_amdgcn_rcpf(__builtin_fmaf(0.3275911f, ax, 1.f));
    float p = t * (0.254829592f + t * (-0.284496736f + t * (1.421413741f
              + t * (-1.453152027f + t * 1.061405429f))));
    float erfv = 1.f - p * __expf(-ax * ax);
    erfv = (x < 0.f) ? -erfv : erfv;
    return a * 0.5f * g * (1.f + erfv);
}

// ---------------- batched per-layer weight transpose fp32->bf16 ----------------
// win interleave: a_j -> col (j>>4)*32 + (j&15); g_j -> col (j>>4)*32 + 16 + (j&15)
__global__ void wtrans_layer(const float* __restrict__ wq, const float* __restrict__ wk,
                             const float* __restrict__ wv, const float* __restrict__ wo,
                             const float* __restrict__ win, const float* __restrict__ wout,
                             bf16* __restrict__ dqkv, bf16* __restrict__ dwo,
                             bf16* __restrict__ dwin, bf16* __restrict__ dwout) {
    __shared__ float tile[32][33];
    int bid = blockIdx.x;
    const float* src; bf16* dst; int K, M, Kpad, interleave = 0, local;
    if (bid < 512)       { src = wq;   dst = dqkv;            K = 512;  M = 1024; Kpad = 512;  local = bid; }
    else if (bid < 768)  { src = wk;   dst = dqkv + 1024*512; K = 512;  M = 512;  Kpad = 512;  local = bid - 512; }
    else if (bid < 1024) { src = wv;   dst = dqkv + 1536*512; K = 512;  M = 512;  Kpad = 512;  local = bid - 768; }
    else if (bid < 1536) { src = wo;   dst = dwo;             K = 1024; M = 512;  Kpad = 1024; local = bid - 1024; }
    else if (bid < 2944) { src = win;  dst = dwin;            K = 512;  M = 2730; Kpad = 512;  local = bid - 1536; interleave = 1; }
    else                 { src = wout; dst = dwout;           K = 1365; M = 512;  Kpad = 1408; local = bid - 2944; }
    int tilesx = Kpad >> 5;
    int k0 = (local % tilesx) * 32, m0 = (local / tilesx) * 32;
    int tx = threadIdx.x & 31, ty = threadIdx.x >> 5;
    #pragma unroll
    for (int i = 0; i < 4; ++i) {
        int k = k0 + ty + 8 * i, m = m0 + tx;
        tile[ty + 8 * i][tx] = (k < K && m < M) ? src[(size_t)k * M + m] : 0.f;
    }
    __syncthreads();
    #pragma unroll
    for (int i = 0; i < 4; ++i) {
        int n = m0 + ty + 8 * i, k = k0 + tx;
        int nd = n;
        if (interleave) {
            if (n < DII)        nd = ((n >> 4) << 5) + (n & 15);
            else if (n < DI2) { int m = n - DII; nd = ((m >> 4) << 5) + 16 + (m & 15); }
            else              { int q = n - DI2; int j = DII + (q >> 1);
                                nd = ((j >> 4) << 5) + ((q & 1) << 4) + (j & 15); }
        }
        dst[(size_t)nd * Kpad + k] = __float2bfloat16(tile[tx][ty + 8 * i]);
    }
}

// ---------------- RMSNorm: one wave per row, float4 loads, shuffle reduce ----------------
template<int BF16OUT>
__global__ __launch_bounds__(256)
void rms_kernel(const float* __restrict__ x, const float* __restrict__ w,
                void* __restrict__ out, int perm) {
    int wave = threadIdx.x >> 6, lane = threadIdx.x & 63;
    int r = blockIdx.x * 4 + wave;
    int src = r;
    if (perm) {
        int t = r & 15; int rs = r >> 4; int s = rs % SSQ; int b = rs / SSQ;
        src = (b * TT + t) * SSQ + s;
    }
    const float4* xr = (const float4*)(x + (size_t)src * DIMD) + lane * 2;
    float4 a = xr[0], c = xr[1];
    float ss = a.x*a.x + a.y*a.y + a.z*a.z + a.w*a.w
             + c.x*c.x + c.y*c.y + c.z*c.z + c.w*c.w;
    ss += __shfl_xor(ss, 1);  ss += __shfl_xor(ss, 2);  ss += __shfl_xor(ss, 4);
    ss += __shfl_xor(ss, 8);  ss += __shfl_xor(ss, 16); ss += __shfl_xor(ss, 32);
    float sc = rsqrtf(ss * (1.f / DIMD) + EPSR);
    const float4* wr = (const float4*)w + lane * 2;
    float4 wa = wr[0], wb = wr[1];
    if (BF16OUT) {
        short8 v;
        v[0] = f2bfs(a.x * sc * wa.x); v[1] = f2bfs(a.y * sc * wa.y);
        v[2] = f2bfs(a.z * sc * wa.z); v[3] = f2bfs(a.w * sc * wa.w);
        v[4] = f2bfs(c.x * sc * wb.x); v[5] = f2bfs(c.y * sc * wb.y);
        v[6] = f2bfs(c.z * sc * wb.z); v[7] = f2bfs(c.w * sc * wb.w);
        *(short8*)((bf16*)out + (size_t)r * DIMD + lane * 8) = v;
    } else {
        float4* o = (float4*)((float*)out + (size_t)r * DIMD) + lane * 2;
        float4 o0 = {a.x * sc * wa.x, a.y * sc * wa.y, a.z * sc * wa.z, a.w * sc * wa.w};
        float4 o1 = {c.x * sc * wb.x, c.y * sc * wb.y, c.z * sc * wb.z, c.w * sc * wb.w};
        o[0] = o0; o[1] = o1;
    }
}

// ---------------- panel MFMA GEMM: B-panel resident in LDS, barrier-free loop --------
// K=512: full 128-col B panel = 128KB = one LDS, loaded once (transposed granule
// layout). No barriers after: each of 8 waves streams its own m-frags, A direct
// from global (L2/L3-hot, XCD-swizzled), 1-deep A prefetch, 8 MFMA per K-step.
// EPI: 1 = qkv + fused l2norm/gamma/rotary; 2 = glu (block-16 interleaved a/g).
template<int EPI>
__global__ __launch_bounds__(512, 1)
void mfma_gemm_panel(const bf16* __restrict__ A, int lda,
                     const bf16* __restrict__ Bt, int ldb,
                     const float* __restrict__ bias,
                     void* __restrict__ C, int ldc,
                     int nrow, int mchunk,
                     const float* __restrict__ qg, const float* __restrict__ kg,
                     int rotary) {
    __shared__ __align__(16) short lds_b[128 * 512];   // 128 KB
    // T1: bijective XCD-aware remap (m204)
    int gx = gridDim.x;
    int nwg = gx * gridDim.y;
    int lin = blockIdx.y * gx + blockIdx.x;
    int q8 = nwg >> 3, r8 = nwg & 7;
    int xcd = lin & 7, idx = lin >> 3;
    int wsw = (xcd < r8 ? xcd * (q8 + 1) : r8 * (q8 + 1) + (xcd - r8) * q8) + idx;
    int bx = wsw % gx, by = wsw / gx;
    int n0 = bx * 128, m0 = by * mchunk;

    int tid = threadIdx.x;
    int wave = tid >> 6, lane = tid & 63;
    int quad = lane >> 4, l16 = lane & 15;

    // stage B panel: 8192 granules of 16B; granule gi: c = gi>>7, n = gi&127
    const short* Bp = (const short*)Bt;
    #pragma unroll
    for (int j = 0; j < 16; ++j) {
        int gi = tid + 512 * j;
        int n = gi & 127, c = gi >> 7;
        async16(Bp + (size_t)(n0 + n) * ldb + c * 8, &lds_b[gi * 8]);
    }
    const short* Ap = (const short*)A;

    // hoisted epilogue constants
    float gl[2][4];
    float c0r[4], s0r[4], c1r[4], s1r[4];
    bool isqk = false;
    float ba[4], bg[4];
    if constexpr (EPI == 1) {
        int headb = n0 >> 6;
        isqk = headb < 24;
        if (isqk) {
            #pragma unroll
            for (int hh = 0; hh < 2; ++hh) {
                int head = headb + hh;
                const float* g = head < 16 ? qg + head * 64 : kg + (head - 16) * 64;
                gl[hh][0] = (g[l16] + 1.f) * 8.f;
                gl[hh][1] = (g[16 + l16] + 1.f) * 8.f;
                gl[hh][2] = (g[32 + l16] + 1.f) * 8.f;
                gl[hh][3] = (g[48 + l16] + 1.f) * 8.f;
            }
        }
        if (rotary) {
            float inv0 = __expf(-(float)l16 * 0.28782313662425572f);        // ln(1e4)/32
            float inv1 = __expf(-(float)(l16 + 16) * 0.28782313662425572f);
            #pragma unroll
            for (int e = 0; e < 4; ++e) {
                float t = (float)(quad * 4 + e);
                c0r[e] = __cosf(t * inv0); s0r[e] = __sinf(t * inv0);
                c1r[e] = __cosf(t * inv1); s1r[e] = __sinf(t * inv1);
            }
        }
    } else {
        int jb = n0 >> 1;
        #pragma unroll
        for (int t = 0; t < 4; ++t) {
            int j = jb + t * 16 + l16;
            ba[t] = (j < DII) ? bias[j] : 0.f;
            bg[t] = (j < DII) ? bias[DII + j] : 0.f;
        }
    }
    __syncthreads();   // B panel resident (drains vmcnt before barrier)

    int base_b = (quad * 128 + l16) * 16;   // byte addr of granule (c=quad, n=l16)
    int nfrag = mchunk >> 4;
    for (int f = wave; f < nfrag; f += 8) {
        int mrow = m0 + f * 16 + l16;
        if (mrow >= nrow) mrow = nrow - 1;          // clamp; C-write guarded below
        const short* ap = Ap + (size_t)mrow * lda + quad * 8;
        f32x4 acc[8];
        #pragma unroll
        for (int nj = 0; nj < 8; ++nj) acc[nj] = {0.f, 0.f, 0.f, 0.f};
        short8 a = *(const short8*)ap;
        short8 anext = a;
        #pragma unroll
        for (int kt = 0; kt < 16; ++kt) {
            if (kt < 15) anext = *(const short8*)(ap + (kt + 1) * 32);
            const char* vb = (const char*)lds_b + base_b + kt * 8192;
            __builtin_amdgcn_s_setprio(1);
            #pragma unroll
            for (int nj = 0; nj < 8; ++nj) {
                short8 b = *(const short8*)(vb + nj * 256);
                acc[nj] = __builtin_amdgcn_mfma_f32_16x16x32_bf16(a, b, acc[nj], 0, 0, 0);
            }
            __builtin_amdgcn_s_setprio(0);
            a = anext;
        }
        if constexpr (EPI == 1) {
            #pragma unroll
            for (int hh = 0; hh < 2; ++hh) {
                #pragma unroll
                for (int e = 0; e < 4; ++e) {
                    int row = m0 + f * 16 + quad * 4 + e;
                    float v0 = acc[hh * 4 + 0][e], v1 = acc[hh * 4 + 1][e];
                    float v2 = acc[hh * 4 + 2][e], v3 = acc[hh * 4 + 3][e];
                    if (isqk) {
                        float ss = v0 * v0 + v1 * v1 + v2 * v2 + v3 * v3;
                        ss += __shfl_xor(ss, 1); ss += __shfl_xor(ss, 2);
                        ss += __shfl_xor(ss, 4); ss += __shfl_xor(ss, 8);
                        float invn = 1.f / fmaxf(sqrtf(ss), 1e-12f);
                        v0 *= invn * gl[hh][0]; v1 *= invn * gl[hh][1];
                        v2 *= invn * gl[hh][2]; v3 *= invn * gl[hh][3];
                        if (rotary) {
                            float n0v = v0 * c0r[e] - v2 * s0r[e];
                            float n1v = v1 * c1r[e] - v3 * s1r[e];
                            float n2v = v2 * c0r[e] + v0 * s0r[e];
                            float n3v = v3 * c1r[e] + v1 * s1r[e];
                            v0 = n0v; v1 = n1v; v2 = n2v; v3 = n3v;
                        }
                    }
                    if (row < nrow) {
                        bf16* p = (bf16*)C + (size_t)row * ldc + n0 + hh * 64 + l16;
                        p[0]  = __float2bfloat16(v0);
                        p[16] = __float2bfloat16(v1);
                        p[32] = __float2bfloat16(v2);
                        p[48] = __float2bfloat16(v3);
                    }
                }
            }
        } else {
            int jb = n0 >> 1;
            #pragma unroll
            for (int e = 0; e < 4; ++e) {
                int row = m0 + f * 16 + quad * 4 + e;
                if (row < nrow) {
                    bf16* cr = (bf16*)C + (size_t)row * ldc;
                    #pragma unroll
                    for (int t = 0; t < 4; ++t)
                        cr[jb + t * 16 + l16] = __float2bfloat16(
                            glu_fast(acc[2 * t][e] + ba[t], acc[2 * t + 1][e] + bg[t]));
                }
            }
        }
    }
}

// ---------------- MFMA bf16 GEMM (small): C[nrow,M] = A @ Bt^T ----------------
// TM x 128 tile, BK=32, double-buffered, granule swizzle kc' = kc^((m>>1)&3).
// 4 waves. EPI 3 = fp32 accumulate (+= into C), optional PERM store.
template<int EPI, int PERM, int TM>
__global__ __launch_bounds__(256)
void mfma_gemm(const bf16* __restrict__ A, int lda,
               const bf16* __restrict__ Bt, int ldb,
               const float* __restrict__ bias,
               void* __restrict__ C, int ldc, int Mstore,
               int nrow, int K) {
    constexpr int MI = TM / 32;
    constexpr int ALW = TM / 64;
    __shared__ __align__(16) short lds_a[2][TM * 32];
    __shared__ __align__(16) short lds_b[2][128 * 32];
    int tid = threadIdx.x;
    int wave = tid >> 6, lane = tid & 63;
    int quad = lane >> 4, l16 = lane & 15;
    int m0 = blockIdx.y * TM, n0 = blockIdx.x * 128;
    int wm = (wave & 1) * (TM / 2), wn = (wave >> 1) * 64;
    f32x4 zero4 = {0.f, 0.f, 0.f, 0.f};
    f32x4 acc[MI][4];
    #pragma unroll
    for (int i = 0; i < MI; ++i)
        #pragma unroll
        for (int j = 0; j < 4; ++j) acc[i][j] = zero4;

    const short* Ap = (const short*)A;
    const short* Bp = (const short*)Bt;
    auto aptr = [&](int g) {
        int m = g >> 2, kc = (g & 3) ^ ((g >> 3) & 3);
        int r = m0 + m; if (r >= nrow) r = nrow - 1;
        return Ap + (size_t)r * lda + kc * 8;
    };
    auto bptr = [&](int g) {
        int m = g >> 2, kc = (g & 3) ^ ((g >> 3) & 3);
        return Bp + (size_t)(n0 + m) * ldb + kc * 8;
    };
    const short* gA[ALW]; int aoff[ALW];
    #pragma unroll
    for (int j = 0; j < ALW; ++j) {
        gA[j] = aptr(wave * TM + j * 64 + lane);
        aoff[j] = (wave * TM + j * 64) * 8;
    }
    const short* gB0 = bptr(wave * 128 + lane);
    const short* gB1 = bptr(wave * 128 + 64 + lane);
    int boff0 = (wave * 128) * 8, boff1 = (wave * 128 + 64) * 8;

    auto stage = [&](int buf, int kt) {
        int ko = kt * 32;
        #pragma unroll
        for (int j = 0; j < ALW; ++j)
            async16(gA[j] + ko, &lds_a[buf][aoff[j]]);
        async16(gB0 + ko, &lds_b[buf][boff0]);
        async16(gB1 + ko, &lds_b[buf][boff1]);
    };

    int nk = K >> 5;
    stage(0, 0);
    for (int kt = 0; kt < nk; ++kt) {
        int buf = kt & 1;
        __syncthreads();
        if (kt + 1 < nk) stage(buf ^ 1, kt + 1);
        short8 af[MI], bfr[4];
        #pragma unroll
        for (int mi = 0; mi < MI; ++mi) {
            int m = wm + mi * 16 + l16;
            af[mi] = *(const short8*)&lds_a[buf][(m * 4 + (quad ^ ((m >> 1) & 3))) * 8];
        }
        #pragma unroll
        for (int nj = 0; nj < 4; ++nj) {
            int n = wn + nj * 16 + l16;
            bfr[nj] = *(const short8*)&lds_b[buf][(n * 4 + (quad ^ ((n >> 1) & 3))) * 8];
        }
        #pragma unroll
        for (int mi = 0; mi < MI; ++mi)
            #pragma unroll
            for (int nj = 0; nj < 4; ++nj)
                acc[mi][nj] = __builtin_amdgcn_mfma_f32_16x16x32_bf16(
                    af[mi], bfr[nj], acc[mi][nj], 0, 0, 0);
    }

    #pragma unroll
    for (int mi = 0; mi < MI; ++mi) {
        #pragma unroll
        for (int e = 0; e < 4; ++e) {
            int row = m0 + wm + mi * 16 + quad * 4 + e;
            if (row >= nrow) continue;
            int orow = row;
            if (PERM) {
                int t = row & 15; int rs = row >> 4; int s = rs % SSQ; int b = rs / SSQ;
                orow = (b * TT + t) * SSQ + s;
            }
            #pragma unroll
            for (int nj = 0; nj < 4; ++nj) {
                int col = n0 + wn + nj * 16 + l16;
                if (col >= Mstore) continue;
                float v = acc[mi][nj][e];
                if (bias) v += bias[col];
                ((float*)C)[(size_t)orow * ldc + col] += v;
            }
        }
    }
}

// ---------------- space attention: fused per-(bt,kh) block, ONLINE softmax+PV --------
// One 512-thread block per (bt,kh): K staged once (XOR-granule), V staged once
// transposed (granule (d, kc^(d&7))). Per wave, per fragment: iterate 9 chunks of
// 32 keys; each chunk = 4 QK MFMA + exp (online sum) + 8 shuffles + 4 PV MFMA.
// NO sc[18] score array -> no VGPR spill (round-8 lesson: 128 VGPR + scratch
// round-trip of 18 f32x4/lane was 60+MB of scratch traffic per dispatch).
// Iteration order identical to the 2-pass version -> bit-identical results.
__global__ __launch_bounds__(512)
void space_attn_kernel(const bf16* __restrict__ qkv, bf16* __restrict__ ob) {
    __shared__ __align__(16) short kls[272 * 8 * 8];   // 34KB: granule (key,c) = K[key][8*(c^(key&7))..]
    __shared__ __align__(16) short vls[64 * SKP2];     // 40KB: granule (d,kc^(d&7)) = V^T[d][kc*8..+8]
    int bt = blockIdx.x, kh = blockIdx.y;
    int tid = threadIdx.x, wave = tid >> 6, lane = tid & 63;
    int quad = lane >> 4, l16 = lane & 15;
    const short* qbase = (const short*)qkv + (size_t)bt * SSQ * 2048;
    const short* kgbase = qbase + 1024 + kh * 64;
    const short* vgbase = qbase + 1536 + kh * 64;

    // stage K: 272 keys x 8 chunks = 2176 granules of 16B (async, pre-swizzled src)
    #pragma unroll
    for (int u = 0; u < 5; ++u) {
        int g = u * 512 + tid;
        if (g < 2176) {
            int key = g >> 3, ch = g & 7;
            int srck = key < SSQ ? key : 256;
            async16(kgbase + (size_t)srck * 2048 + (ch ^ (key & 7)) * 8, &kls[g * 8]);
        }
    }
    // stage V transposed: read 16B of V[key][c*8..], scatter to vls[d][key]
    #pragma unroll
    for (int u = 0; u < 5; ++u) {
        int g = u * 512 + tid;
        if (g < 2176) {
            int key = g >> 3, c = g & 7;
            int srck = key < SSQ ? key : 256;
            short8 vv = *(const short8*)(vgbase + (size_t)srck * 2048 + c * 8);
            int kc = key >> 3, kl = key & 7;
            #pragma unroll
            for (int dd = 0; dd < 8; ++dd) {
                int d = c * 8 + dd;
                vls[(d * 40 + (kc ^ (d & 7))) * 8 + kl] = vv[dd];
            }
        }
    }
    // zero chunks kc=34,35 (keys 272..287, read by PV c8=8 but never written)
    if (tid < 128) {
        int d = tid >> 1, kc = 34 + (tid & 1);
        short8 z8 = {0, 0, 0, 0, 0, 0, 0, 0};
        *(short8*)&vls[(d * 40 + (kc ^ (d & 7))) * 8] = z8;
    }
    __syncthreads();   // drains vmcnt (K) + lgkm (V writes)

    f32x4 zero4 = {0.f, 0.f, 0.f, 0.f};
    int c0 = quad ^ (l16 & 7);
    int d7 = l16 & 7;          // (nt*16+l16)&7 == l16&7
    for (int f = wave; f < 34; f += 8) {
        int qh_l = (f >= 17) ? 1 : 0;
        int qt = f - qh_l * 17;
        int qh = kh * 2 + qh_l;
        int q = qt * 16 + l16;
        int qc = q > 256 ? 256 : q;
        const short* qp = qbase + (size_t)qc * 2048 + qh * 64;
        short8 bq0 = *(const short8*)(qp + quad * 8);
        short8 bq1 = *(const short8*)(qp + 32 + quad * 8);

        float sum = 0.f;
        f32x4 oacc[4];
        #pragma unroll
        for (int nt = 0; nt < 4; ++nt) oacc[nt] = zero4;

        #pragma unroll
        for (int c8 = 0; c8 < 9; ++c8) {
            f32x4 s0 = zero4, s1 = zero4;
            #pragma unroll
            for (int half = 0; half < 2; ++half) {
                int kt = c8 * 2 + half;
                if (kt < 17) {
                    int key = kt * 16 + l16;
                    short8 ak0 = *(const short8*)&kls[(key * 8 + c0) * 8];
                    short8 ak1 = *(const short8*)&kls[(key * 8 + (c0 ^ 4)) * 8];
                    f32x4 cc = zero4;
                    cc = __builtin_amdgcn_mfma_f32_16x16x32_bf16(ak0, bq0, cc, 0, 0, 0);
                    cc = __builtin_amdgcn_mfma_f32_16x16x32_bf16(ak1, bq1, cc, 0, 0, 0);
                    #pragma unroll
                    for (int e = 0; e < 4; ++e) {
                        float x = cc[e] * 0.0025f;           // s/50, s = dot/8
                        float x2 = x * x;
                        float v = cc[e] * 0.125f * (1.f + x2 * (-0.3333333333f + x2 * 0.1333333333f));
                        float p = __expf(v);                 // v in [-8.1, 8.1]: no overflow
                        if (kt == 16) {
                            bool valid = (e == 0) && (quad == 0) && (q == 256);
                            p = valid ? p : 0.f;
                        }
                        cc[e] = p;
                        sum += p;
                    }
                    if (half) s1 = cc; else s0 = cc;
                }
            }
            short8 pb;
            #pragma unroll
            for (int j = 0; j < 8; ++j) {
                int src_lane = ((quad & 1) * 2 + (j >> 2)) * 16 + l16;
                float v0 = __shfl(s0[j & 3], src_lane);
                float v1 = __shfl(s1[j & 3], src_lane);
                pb[j] = f2bfs(quad < 2 ? v0 : v1);
            }
            #pragma unroll
            for (int nt = 0; nt < 4; ++nt) {
                int d = nt * 16 + l16;
                int kc = (c8 * 4 + quad) ^ d7;
                short8 av = *(const short8*)&vls[(d * 40 + kc) * 8];
                oacc[nt] = __builtin_amdgcn_mfma_f32_16x16x32_bf16(pb, av, oacc[nt], 0, 0, 0);
            }
        }

        sum += __shfl_xor(sum, 16);
        sum += __shfl_xor(sum, 32);
        float inv = __builtin_amdgcn_rcpf(sum);
        f32x4 inv4;
        #pragma unroll
        for (int e = 0; e < 4; ++e) inv4[e] = __shfl(inv, quad * 4 + e);

        #pragma unroll
        for (int e = 0; e < 4; ++e) {
            int qq = qt * 16 + quad * 4 + e;
            if (qq <= 256) {
                bf16* op = ob + ((size_t)(bt * SSQ + qq)) * 1024 + qh * 64 + l16;
                float s = inv4[e];
                op[0]  = __float2bfloat16(oacc[0][e] * s);
                op[16] = __float2bfloat16(oacc[1][e] * s);
                op[32] = __float2bfloat16(oacc[2][e] * s);
                op[48] = __float2bfloat16(oacc[3][e] * s);
            }
        }
    }
}

// ---------------- time attention (n=16, causal): MFMA, one wave per (bs, qh) --------
__global__ __launch_bounds__(256)
void time_attn_kernel(const bf16* __restrict__ qkv, bf16* __restrict__ ob) {
    __shared__ __align__(16) short kls[2 * 16 * 64];    // [khl][key][8 gran], XOR-swizzled
    __shared__ __align__(16) short vls[2 * 64 * 24];    // [khl][d][key pad 24]
    int bs = blockIdx.x, qg = blockIdx.y;
    int tid = threadIdx.x, wave = tid >> 6, lane = tid & 63;
    int quad = lane >> 4, l16 = lane & 15;
    int qh = qg * 4 + wave;
    int khl_w = wave >> 1;
    size_t rowbase = (size_t)bs * 16;
    const short* qbase = (const short*)qkv;

    {
        int c = tid & 7, key = (tid >> 3) & 15, khl = tid >> 7;
        const short* ksrc = qbase + (rowbase + key) * 2048 + 1024 + (qg * 2 + khl) * 64
                            + (c ^ (key & 7)) * 8;
        async16(ksrc, &kls[((khl * 16 + key) * 8 + c) * 8]);
        short8 vv = *(const short8*)(qbase + (rowbase + key) * 2048 + 1536
                                     + (qg * 2 + khl) * 64 + c * 8);
        #pragma unroll
        for (int dd = 0; dd < 8; ++dd)
            vls[(khl * 64 + c * 8 + dd) * 24 + key] = vv[dd];
    }
    const short* qp = qbase + (rowbase + l16) * 2048 + qh * 64;
    short8 bq0 = *(const short8*)(qp + quad * 8);
    short8 bq1 = *(const short8*)(qp + 32 + quad * 8);
    __syncthreads();

    int c0 = quad ^ (l16 & 7);
    const short* kw = &kls[(khl_w * 16 + l16) * 64];
    short8 ak0 = *(const short8*)(kw + c0 * 8);
    short8 ak1 = *(const short8*)(kw + (c0 ^ 4) * 8);
    f32x4 cc = {0.f, 0.f, 0.f, 0.f};
    cc = __builtin_amdgcn_mfma_f32_16x16x32_bf16(ak0, bq0, cc, 0, 0, 0);
    cc = __builtin_amdgcn_mfma_f32_16x16x32_bf16(ak1, bq1, cc, 0, 0, 0);
    float sum = 0.f;
    #pragma unroll
    for (int e = 0; e < 4; ++e) {
        float s = cc[e] * 0.125f;
        float x = s * 0.02f, x2 = x * x;
        float v = s * (1.f + x2 * (-0.3333333333f + x2 * 0.1333333333f));
        float p = ((quad * 4 + e) > l16) ? 0.f : __expf(v);
        cc[e] = p;
        sum += p;
    }
    sum += __shfl_xor(sum, 16);
    sum += __shfl_xor(sum, 32);
    float inv = __builtin_amdgcn_rcpf(sum);
    f32x4 inv4;
    #pragma unroll
    for (int e = 0; e < 4; ++e) inv4[e] = __shfl(inv, quad * 4 + e);

    short8 pa;
    #pragma unroll
    for (int jj = 0; jj < 8; ++jj) {
        int key = quad * 8 + jj;
        int src = ((key >> 2) & 3) * 16 + l16;
        float v = __shfl(cc[jj & 3], src);
        pa[jj] = f2bfs(quad < 2 ? v : 0.f);
    }
    const short* vw = &vls[khl_w * 64 * 24];
    short8 zero8 = {0, 0, 0, 0, 0, 0, 0, 0};
    f32x4 oacc[4];
    #pragma unroll
    for (int nt = 0; nt < 4; ++nt) {
        short8 av = zero8;
        if (quad < 2)
            av = *(const short8*)(vw + (nt * 16 + l16) * 24 + quad * 8);
        f32x4 z = {0.f, 0.f, 0.f, 0.f};
        oacc[nt] = __builtin_amdgcn_mfma_f32_16x16x32_bf16(pa, av, z, 0, 0, 0);
    }
    #pragma unroll
    for (int e = 0; e < 4; ++e) {
        int q = quad * 4 + e;
        bf16* op = ob + (rowbase + q) * 1024 + qh * 64 + l16;
        float s = inv4[e];
        op[0]  = __float2bfloat16(oacc[0][e] * s);
        op[16] = __float2bfloat16(oacc[1][e] * s);
        op[32] = __float2bfloat16(oacc[2][e] * s);
        op[48] = __float2bfloat16(oacc[3][e] * s);
    }
}

// ---------------- host-side launch ----------------
extern "C" void kernel_launch(void* const* d_in, const int* in_sizes, int n_in,
                              void* d_out, int out_size, void* d_ws, size_t ws_size,
                              hipStream_t stream) {
    const float* tokens      = (const float*)d_in[0];
    const float* attn_norm_w = (const float*)d_in[1];
    const float* Wq          = (const float*)d_in[2];
    const float* Wk          = (const float*)d_in[3];
    const float* Wv          = (const float*)d_in[4];
    const float* q_gamma     = (const float*)d_in[5];
    const float* k_gamma     = (const float*)d_in[6];
    const float* Wo          = (const float*)d_in[7];
    const float* ff_norm_w   = (const float*)d_in[8];
    const float* W_in        = (const float*)d_in[9];
    const float* b_in        = (const float*)d_in[10];
    const float* W_out       = (const float*)d_in[11];
    const float* b_out       = (const float*)d_in[12];
    const float* final_w     = (const float*)d_in[13];

    float* x = (float*)d_out;
    char* ws = (char*)d_ws;

    bf16* wtqkv = (bf16*)ws;                     // [2048][512]
    bf16* wto   = wtqkv + 2048 * 512;            // [512][1024]
    bf16* wtin  = wto   + 512 * 1024;            // [2816][512] interleaved
    bf16* wtout = wtin  + 2816 * 512;            // [512][1408]
    size_t off = (size_t)(2048*512 + 512*1024 + 2816*512 + 512*1408) * 2;
    bf16* h = (bf16*)(ws + off);                 // [N][512]
    off += (size_t)NROWS * 512 * 2;
    char* region = ws + off;
    bf16* qkv = (bf16*)region;                               // [N][2048]
    bf16* glu = (bf16*)region;                               // [N][1408] (FF alias)
    bf16* ob  = (bf16*)(region + (size_t)NROWS * 2048 * 2 + (size_t)256*64*SKP*2);  // [N][1024]

    hipMemcpyAsync(x, tokens, (size_t)NROWS * 512 * 4, hipMemcpyDeviceToDevice, stream);

    for (int l = 0; l < 8; ++l) {
        int is_time = ((l + 1) % 4 == 0) ? 1 : 0;
        wtrans_layer<<<3648, 256, 0, stream>>>(
            Wq + (size_t)l * 512 * 1024, Wk + (size_t)l * 512 * 512,
            Wv + (size_t)l * 512 * 512, Wo + (size_t)l * 1024 * 512,
            W_in + (size_t)l * 512 * DI2, W_out + (size_t)l * DII * 512,
            wtqkv, wto, wtin, wtout);

        // ---- attention block ----
        rms_kernel<1><<<2056, 256, 0, stream>>>(x, attn_norm_w + (size_t)l * 512, h, is_time);
        mfma_gemm_panel<1><<<dim3(16, 16), 512, 0, stream>>>(
            h, 512, wtqkv, 512, nullptr, qkv, 2048, NROWS, 528,
            q_gamma + (size_t)l * 1024, k_gamma + (size_t)l * 512, is_time);
        if (is_time) {
            time_attn_kernel<<<dim3(514, 4), 256, 0, stream>>>(qkv, ob);
            mfma_gemm<3, 1, 64><<<dim3(4, 129), 256, 0, stream>>>(
                ob, 1024, wto, 1024, nullptr, x, 512, 512, NROWS, 1024);
        } else {
            space_attn_kernel<<<dim3(32, 8), 512, 0, stream>>>(qkv, ob);
            mfma_gemm<3, 0, 64><<<dim3(4, 129), 256, 0, stream>>>(
                ob, 1024, wto, 1024, nullptr, x, 512, 512, NROWS, 1024);
        }

        // ---- feed-forward block ----
        rms_kernel<1><<<2056, 256, 0, stream>>>(x, ff_norm_w + (size_t)l * 512, h, 0);
        mfma_gemm_panel<2><<<dim3(22, 11), 512, 0, stream>>>(
            h, 512, wtin, 512, b_in + (size_t)l * DI2, glu, GLULD, NROWS, 768,
            nullptr, nullptr, 0);
        mfma_gemm<3, 0, 64><<<dim3(4, 129), 256, 0, stream>>>(
            glu, GLULD, wtout, GLULD, b_out + (size_t)l * 512, x, 512, 512, NROWS, GLULD);
    }

    rms_kernel<0><<<2056, 256, 0, stream>>>(x, final_w, x, 0);
}

// Round 11
// 1861.500 us; speedup vs baseline: 1.1506x; 1.0017x over previous
//
#include <hip/hip_runtime.h>
#include <hip/hip_bf16.h>
#include <math.h>

typedef __attribute__((ext_vector_type(8))) short short8;
typedef __attribute__((ext_vector_type(4))) float f32x4;
typedef __hip_bfloat16 bf16;

#define BB 2
#define TT 16
#define SSQ 257
#define DIMD 512
#define NROWS 8224          // B*T*S
#define DII 1365
#define DI2 2730
#define FNPAD 2816          // ff_in N padded (22*128), block-16 interleaved a/g
#define GLULD 1408          // glu row stride / ff_out K (44*32)
#define SKP 288             // legacy pad (workspace layout only)
#define SKP2 320            // V LDS pad: 40 chunks of 8 keys
#define EPSR 1.1920929e-07f

__device__ __forceinline__ void async16(const void* g, const void* l) {
    __builtin_amdgcn_global_load_lds(
        (const __attribute__((address_space(1))) void*)g,
        (__attribute__((address_space(3))) void*)l, 16, 0, 0);
}

__device__ __forceinline__ short f2bfs(float x) {
    bf16 h = __float2bfloat16(x);
    return *reinterpret_cast<short*>(&h);
}

// fast exact-gelu: a * g * Phi(g), erf via A&S 7.1.26 (abs err 1.5e-7)
__device__ __forceinline__ float glu_fast(float a, float g) {
    float x = g * 0.70710678118654752f;
    float ax = fabsf(x);
    float t = __builtin_amdgcn_rcpf(__builtin_fmaf(0.3275911f, ax, 1.f));
    float p = t * (0.254829592f + t * (-0.284496736f + t * (1.421413741f
              + t * (-1.453152027f + t * 1.061405429f))));
    float erfv = 1.f - p * __expf(-ax * ax);
    erfv = (x < 0.f) ? -erfv : erfv;
    return a * 0.5f * g * (1.f + erfv);
}

// ---------------- batched per-layer weight transpose fp32->bf16 ----------------
// win interleave: a_j -> col (j>>4)*32 + (j&15); g_j -> col (j>>4)*32 + 16 + (j&15)
__global__ void wtrans_layer(const float* __restrict__ wq, const float* __restrict__ wk,
                             const float* __restrict__ wv, const float* __restrict__ wo,
                             const float* __restrict__ win, const float* __restrict__ wout,
                             bf16* __restrict__ dqkv, bf16* __restrict__ dwo,
                             bf16* __restrict__ dwin, bf16* __restrict__ dwout) {
    __shared__ float tile[32][33];
    int bid = blockIdx.x;
    const float* src; bf16* dst; int K, M, Kpad, interleave = 0, local;
    if (bid < 512)       { src = wq;   dst = dqkv;            K = 512;  M = 1024; Kpad = 512;  local = bid; }
    else if (bid < 768)  { src = wk;   dst = dqkv + 1024*512; K = 512;  M = 512;  Kpad = 512;  local = bid - 512; }
    else if (bid < 1024) { src = wv;   dst = dqkv + 1536*512; K = 512;  M = 512;  Kpad = 512;  local = bid - 768; }
    else if (bid < 1536) { src = wo;   dst = dwo;             K = 1024; M = 512;  Kpad = 1024; local = bid - 1024; }
    else if (bid < 2944) { src = win;  dst = dwin;            K = 512;  M = 2730; Kpad = 512;  local = bid - 1536; interleave = 1; }
    else                 { src = wout; dst = dwout;           K = 1365; M = 512;  Kpad = 1408; local = bid - 2944; }
    int tilesx = Kpad >> 5;
    int k0 = (local % tilesx) * 32, m0 = (local / tilesx) * 32;
    int tx = threadIdx.x & 31, ty = threadIdx.x >> 5;
    #pragma unroll
    for (int i = 0; i < 4; ++i) {
        int k = k0 + ty + 8 * i, m = m0 + tx;
        tile[ty + 8 * i][tx] = (k < K && m < M) ? src[(size_t)k * M + m] : 0.f;
    }
    __syncthreads();
    #pragma unroll
    for (int i = 0; i < 4; ++i) {
        int n = m0 + ty + 8 * i, k = k0 + tx;
        int nd = n;
        if (interleave) {
            if (n < DII)        nd = ((n >> 4) << 5) + (n & 15);
            else if (n < DI2) { int m = n - DII; nd = ((m >> 4) << 5) + 16 + (m & 15); }
            else              { int q = n - DI2; int j = DII + (q >> 1);
                                nd = ((j >> 4) << 5) + ((q & 1) << 4) + (j & 15); }
        }
        dst[(size_t)nd * Kpad + k] = __float2bfloat16(tile[tx][ty + 8 * i]);
    }
}

// ---------------- RMSNorm: one wave per row, float4 loads, shuffle reduce ----------------
template<int BF16OUT>
__global__ __launch_bounds__(256)
void rms_kernel(const float* __restrict__ x, const float* __restrict__ w,
                void* __restrict__ out, int perm) {
    int wave = threadIdx.x >> 6, lane = threadIdx.x & 63;
    int r = blockIdx.x * 4 + wave;
    int src = r;
    if (perm) {
        int t = r & 15; int rs = r >> 4; int s = rs % SSQ; int b = rs / SSQ;
        src = (b * TT + t) * SSQ + s;
    }
    const float4* xr = (const float4*)(x + (size_t)src * DIMD) + lane * 2;
    float4 a = xr[0], c = xr[1];
    float ss = a.x*a.x + a.y*a.y + a.z*a.z + a.w*a.w
             + c.x*c.x + c.y*c.y + c.z*c.z + c.w*c.w;
    ss += __shfl_xor(ss, 1);  ss += __shfl_xor(ss, 2);  ss += __shfl_xor(ss, 4);
    ss += __shfl_xor(ss, 8);  ss += __shfl_xor(ss, 16); ss += __shfl_xor(ss, 32);
    float sc = rsqrtf(ss * (1.f / DIMD) + EPSR);
    const float4* wr = (const float4*)w + lane * 2;
    float4 wa = wr[0], wb = wr[1];
    if (BF16OUT) {
        short8 v;
        v[0] = f2bfs(a.x * sc * wa.x); v[1] = f2bfs(a.y * sc * wa.y);
        v[2] = f2bfs(a.z * sc * wa.z); v[3] = f2bfs(a.w * sc * wa.w);
        v[4] = f2bfs(c.x * sc * wb.x); v[5] = f2bfs(c.y * sc * wb.y);
        v[6] = f2bfs(c.z * sc * wb.z); v[7] = f2bfs(c.w * sc * wb.w);
        *(short8*)((bf16*)out + (size_t)r * DIMD + lane * 8) = v;
    } else {
        float4* o = (float4*)((float*)out + (size_t)r * DIMD) + lane * 2;
        float4 o0 = {a.x * sc * wa.x, a.y * sc * wa.y, a.z * sc * wa.z, a.w * sc * wa.w};
        float4 o1 = {c.x * sc * wb.x, c.y * sc * wb.y, c.z * sc * wb.z, c.w * sc * wb.w};
        o[0] = o0; o[1] = o1;
    }
}

// ---------------- panel MFMA GEMM: B-panel resident in LDS, barrier-free loop --------
// K=512: full 128-col B panel = 128KB = one LDS, loaded once (transposed granule
// layout). No barriers after: each of 8 waves streams its own m-frags, A direct
// from global (L2/L3-hot, XCD-swizzled), 1-deep A prefetch, 8 MFMA per K-step.
// EPI: 1 = qkv + fused l2norm/gamma/rotary; 2 = glu (block-16 interleaved a/g).
template<int EPI>
__global__ __launch_bounds__(512, 1)
void mfma_gemm_panel(const bf16* __restrict__ A, int lda,
                     const bf16* __restrict__ Bt, int ldb,
                     const float* __restrict__ bias,
                     void* __restrict__ C, int ldc,
                     int nrow, int mchunk,
                     const float* __restrict__ qg, const float* __restrict__ kg,
                     int rotary) {
    __shared__ __align__(16) short lds_b[128 * 512];   // 128 KB
    // T1: bijective XCD-aware remap (m204)
    int gx = gridDim.x;
    int nwg = gx * gridDim.y;
    int lin = blockIdx.y * gx + blockIdx.x;
    int q8 = nwg >> 3, r8 = nwg & 7;
    int xcd = lin & 7, idx = lin >> 3;
    int wsw = (xcd < r8 ? xcd * (q8 + 1) : r8 * (q8 + 1) + (xcd - r8) * q8) + idx;
    int bx = wsw % gx, by = wsw / gx;
    int n0 = bx * 128, m0 = by * mchunk;

    int tid = threadIdx.x;
    int wave = tid >> 6, lane = tid & 63;
    int quad = lane >> 4, l16 = lane & 15;

    // stage B panel: 8192 granules of 16B; granule gi: c = gi>>7, n = gi&127
    const short* Bp = (const short*)Bt;
    #pragma unroll
    for (int j = 0; j < 16; ++j) {
        int gi = tid + 512 * j;
        int n = gi & 127, c = gi >> 7;
        async16(Bp + (size_t)(n0 + n) * ldb + c * 8, &lds_b[gi * 8]);
    }
    const short* Ap = (const short*)A;

    // hoisted epilogue constants
    float gl[2][4];
    float c0r[4], s0r[4], c1r[4], s1r[4];
    bool isqk = false;
    float ba[4], bg[4];
    if constexpr (EPI == 1) {
        int headb = n0 >> 6;
        isqk = headb < 24;
        if (isqk) {
            #pragma unroll
            for (int hh = 0; hh < 2; ++hh) {
                int head = headb + hh;
                const float* g = head < 16 ? qg + head * 64 : kg + (head - 16) * 64;
                gl[hh][0] = (g[l16] + 1.f) * 8.f;
                gl[hh][1] = (g[16 + l16] + 1.f) * 8.f;
                gl[hh][2] = (g[32 + l16] + 1.f) * 8.f;
                gl[hh][3] = (g[48 + l16] + 1.f) * 8.f;
            }
        }
        if (rotary) {
            float inv0 = __expf(-(float)l16 * 0.28782313662425572f);        // ln(1e4)/32
            float inv1 = __expf(-(float)(l16 + 16) * 0.28782313662425572f);
            #pragma unroll
            for (int e = 0; e < 4; ++e) {
                float t = (float)(quad * 4 + e);
                c0r[e] = __cosf(t * inv0); s0r[e] = __sinf(t * inv0);
                c1r[e] = __cosf(t * inv1); s1r[e] = __sinf(t * inv1);
            }
        }
    } else {
        int jb = n0 >> 1;
        #pragma unroll
        for (int t = 0; t < 4; ++t) {
            int j = jb + t * 16 + l16;
            ba[t] = (j < DII) ? bias[j] : 0.f;
            bg[t] = (j < DII) ? bias[DII + j] : 0.f;
        }
    }
    __syncthreads();   // B panel resident (drains vmcnt before barrier)

    int base_b = (quad * 128 + l16) * 16;   // byte addr of granule (c=quad, n=l16)
    int nfrag = mchunk >> 4;
    for (int f = wave; f < nfrag; f += 8) {
        int mrow = m0 + f * 16 + l16;
        if (mrow >= nrow) mrow = nrow - 1;          // clamp; C-write guarded below
        const short* ap = Ap + (size_t)mrow * lda + quad * 8;
        f32x4 acc[8];
        #pragma unroll
        for (int nj = 0; nj < 8; ++nj) acc[nj] = {0.f, 0.f, 0.f, 0.f};
        short8 a = *(const short8*)ap;
        short8 anext = a;
        #pragma unroll
        for (int kt = 0; kt < 16; ++kt) {
            if (kt < 15) anext = *(const short8*)(ap + (kt + 1) * 32);
            const char* vb = (const char*)lds_b + base_b + kt * 8192;
            __builtin_amdgcn_s_setprio(1);
            #pragma unroll
            for (int nj = 0; nj < 8; ++nj) {
                short8 b = *(const short8*)(vb + nj * 256);
                acc[nj] = __builtin_amdgcn_mfma_f32_16x16x32_bf16(a, b, acc[nj], 0, 0, 0);
            }
            __builtin_amdgcn_s_setprio(0);
            a = anext;
        }
        if constexpr (EPI == 1) {
            #pragma unroll
            for (int hh = 0; hh < 2; ++hh) {
                #pragma unroll
                for (int e = 0; e < 4; ++e) {
                    int row = m0 + f * 16 + quad * 4 + e;
                    float v0 = acc[hh * 4 + 0][e], v1 = acc[hh * 4 + 1][e];
                    float v2 = acc[hh * 4 + 2][e], v3 = acc[hh * 4 + 3][e];
                    if (isqk) {
                        float ss = v0 * v0 + v1 * v1 + v2 * v2 + v3 * v3;
                        ss += __shfl_xor(ss, 1); ss += __shfl_xor(ss, 2);
                        ss += __shfl_xor(ss, 4); ss += __shfl_xor(ss, 8);
                        float invn = 1.f / fmaxf(sqrtf(ss), 1e-12f);
                        v0 *= invn * gl[hh][0]; v1 *= invn * gl[hh][1];
                        v2 *= invn * gl[hh][2]; v3 *= invn * gl[hh][3];
                        if (rotary) {
                            float n0v = v0 * c0r[e] - v2 * s0r[e];
                            float n1v = v1 * c1r[e] - v3 * s1r[e];
                            float n2v = v2 * c0r[e] + v0 * s0r[e];
                            float n3v = v3 * c1r[e] + v1 * s1r[e];
                            v0 = n0v; v1 = n1v; v2 = n2v; v3 = n3v;
                        }
                    }
                    if (row < nrow) {
                        bf16* p = (bf16*)C + (size_t)row * ldc + n0 + hh * 64 + l16;
                        p[0]  = __float2bfloat16(v0);
                        p[16] = __float2bfloat16(v1);
                        p[32] = __float2bfloat16(v2);
                        p[48] = __float2bfloat16(v3);
                    }
                }
            }
        } else {
            int jb = n0 >> 1;
            #pragma unroll
            for (int e = 0; e < 4; ++e) {
                int row = m0 + f * 16 + quad * 4 + e;
                if (row < nrow) {
                    bf16* cr = (bf16*)C + (size_t)row * ldc;
                    #pragma unroll
                    for (int t = 0; t < 4; ++t)
                        cr[jb + t * 16 + l16] = __float2bfloat16(
                            glu_fast(acc[2 * t][e] + ba[t], acc[2 * t + 1][e] + bg[t]));
                }
            }
        }
    }
}

// ---------------- MFMA bf16 GEMM (small): C[nrow,M] = A @ Bt^T ----------------
// TM x 128 tile, BK=32, double-buffered, granule swizzle kc' = kc^((m>>1)&3).
// 4 waves. EPI 3 = fp32 accumulate (+= into C), optional PERM store.
template<int EPI, int PERM, int TM>
__global__ __launch_bounds__(256)
void mfma_gemm(const bf16* __restrict__ A, int lda,
               const bf16* __restrict__ Bt, int ldb,
               const float* __restrict__ bias,
               void* __restrict__ C, int ldc, int Mstore,
               int nrow, int K) {
    constexpr int MI = TM / 32;
    constexpr int ALW = TM / 64;
    __shared__ __align__(16) short lds_a[2][TM * 32];
    __shared__ __align__(16) short lds_b[2][128 * 32];
    int tid = threadIdx.x;
    int wave = tid >> 6, lane = tid & 63;
    int quad = lane >> 4, l16 = lane & 15;
    int m0 = blockIdx.y * TM, n0 = blockIdx.x * 128;
    int wm = (wave & 1) * (TM / 2), wn = (wave >> 1) * 64;
    f32x4 zero4 = {0.f, 0.f, 0.f, 0.f};
    f32x4 acc[MI][4];
    #pragma unroll
    for (int i = 0; i < MI; ++i)
        #pragma unroll
        for (int j = 0; j < 4; ++j) acc[i][j] = zero4;

    const short* Ap = (const short*)A;
    const short* Bp = (const short*)Bt;
    auto aptr = [&](int g) {
        int m = g >> 2, kc = (g & 3) ^ ((g >> 3) & 3);
        int r = m0 + m; if (r >= nrow) r = nrow - 1;
        return Ap + (size_t)r * lda + kc * 8;
    };
    auto bptr = [&](int g) {
        int m = g >> 2, kc = (g & 3) ^ ((g >> 3) & 3);
        return Bp + (size_t)(n0 + m) * ldb + kc * 8;
    };
    const short* gA[ALW]; int aoff[ALW];
    #pragma unroll
    for (int j = 0; j < ALW; ++j) {
        gA[j] = aptr(wave * TM + j * 64 + lane);
        aoff[j] = (wave * TM + j * 64) * 8;
    }
    const short* gB0 = bptr(wave * 128 + lane);
    const short* gB1 = bptr(wave * 128 + 64 + lane);
    int boff0 = (wave * 128) * 8, boff1 = (wave * 128 + 64) * 8;

    auto stage = [&](int buf, int kt) {
        int ko = kt * 32;
        #pragma unroll
        for (int j = 0; j < ALW; ++j)
            async16(gA[j] + ko, &lds_a[buf][aoff[j]]);
        async16(gB0 + ko, &lds_b[buf][boff0]);
        async16(gB1 + ko, &lds_b[buf][boff1]);
    };

    int nk = K >> 5;
    stage(0, 0);
    for (int kt = 0; kt < nk; ++kt) {
        int buf = kt & 1;
        __syncthreads();
        if (kt + 1 < nk) stage(buf ^ 1, kt + 1);
        short8 af[MI], bfr[4];
        #pragma unroll
        for (int mi = 0; mi < MI; ++mi) {
            int m = wm + mi * 16 + l16;
            af[mi] = *(const short8*)&lds_a[buf][(m * 4 + (quad ^ ((m >> 1) & 3))) * 8];
        }
        #pragma unroll
        for (int nj = 0; nj < 4; ++nj) {
            int n = wn + nj * 16 + l16;
            bfr[nj] = *(const short8*)&lds_b[buf][(n * 4 + (quad ^ ((n >> 1) & 3))) * 8];
        }
        #pragma unroll
        for (int mi = 0; mi < MI; ++mi)
            #pragma unroll
            for (int nj = 0; nj < 4; ++nj)
                acc[mi][nj] = __builtin_amdgcn_mfma_f32_16x16x32_bf16(
                    af[mi], bfr[nj], acc[mi][nj], 0, 0, 0);
    }

    #pragma unroll
    for (int mi = 0; mi < MI; ++mi) {
        #pragma unroll
        for (int e = 0; e < 4; ++e) {
            int row = m0 + wm + mi * 16 + quad * 4 + e;
            if (row >= nrow) continue;
            int orow = row;
            if (PERM) {
                int t = row & 15; int rs = row >> 4; int s = rs % SSQ; int b = rs / SSQ;
                orow = (b * TT + t) * SSQ + s;
            }
            #pragma unroll
            for (int nj = 0; nj < 4; ++nj) {
                int col = n0 + wn + nj * 16 + l16;
                if (col >= Mstore) continue;
                float v = acc[mi][nj][e];
                if (bias) v += bias[col];
                ((float*)C)[(size_t)orow * ldc + col] += v;
            }
        }
    }
}

// ---------------- space attention: fused per-(bt,kh) block, ONLINE softmax+PV --------
// One 512-thread block per (bt,kh). Grid = 256 blocks = exactly 1 block/CU, so
// __launch_bounds__(512, 1): without it the compiler targets 2 blocks/CU, caps
// at 128 VGPR and spills ~40MB/dispatch to scratch (round-9 counters: WRITE 57MB
// vs 17MB real, FETCH 101MB vs 50MB, cold dispatch 121us = scratch first-touch).
__global__ __launch_bounds__(512, 1)
void space_attn_kernel(const bf16* __restrict__ qkv, bf16* __restrict__ ob) {
    __shared__ __align__(16) short kls[272 * 8 * 8];   // 34KB: granule (key,c) = K[key][8*(c^(key&7))..]
    __shared__ __align__(16) short vls[64 * SKP2];     // 40KB: granule (d,kc^(d&7)) = V^T[d][kc*8..+8]
    int bt = blockIdx.x, kh = blockIdx.y;
    int tid = threadIdx.x, wave = tid >> 6, lane = tid & 63;
    int quad = lane >> 4, l16 = lane & 15;
    const short* qbase = (const short*)qkv + (size_t)bt * SSQ * 2048;
    const short* kgbase = qbase + 1024 + kh * 64;
    const short* vgbase = qbase + 1536 + kh * 64;

    // stage K: 272 keys x 8 chunks = 2176 granules of 16B (async, pre-swizzled src)
    #pragma unroll
    for (int u = 0; u < 5; ++u) {
        int g = u * 512 + tid;
        if (g < 2176) {
            int key = g >> 3, ch = g & 7;
            int srck = key < SSQ ? key : 256;
            async16(kgbase + (size_t)srck * 2048 + (ch ^ (key & 7)) * 8, &kls[g * 8]);
        }
    }
    // stage V transposed: read 16B of V[key][c*8..], scatter to vls[d][key]
    #pragma unroll
    for (int u = 0; u < 5; ++u) {
        int g = u * 512 + tid;
        if (g < 2176) {
            int key = g >> 3, c = g & 7;
            int srck = key < SSQ ? key : 256;
            short8 vv = *(const short8*)(vgbase + (size_t)srck * 2048 + c * 8);
            int kc = key >> 3, kl = key & 7;
            #pragma unroll
            for (int dd = 0; dd < 8; ++dd) {
                int d = c * 8 + dd;
                vls[(d * 40 + (kc ^ (d & 7))) * 8 + kl] = vv[dd];
            }
        }
    }
    // zero chunks kc=34,35 (keys 272..287, read by PV c8=8 but never written)
    if (tid < 128) {
        int d = tid >> 1, kc = 34 + (tid & 1);
        short8 z8 = {0, 0, 0, 0, 0, 0, 0, 0};
        *(short8*)&vls[(d * 40 + (kc ^ (d & 7))) * 8] = z8;
    }
    __syncthreads();   // drains vmcnt (K) + lgkm (V writes)

    f32x4 zero4 = {0.f, 0.f, 0.f, 0.f};
    int c0 = quad ^ (l16 & 7);
    int d7 = l16 & 7;          // (nt*16+l16)&7 == l16&7
    for (int f = wave; f < 34; f += 8) {
        int qh_l = (f >= 17) ? 1 : 0;
        int qt = f - qh_l * 17;
        int qh = kh * 2 + qh_l;
        int q = qt * 16 + l16;
        int qc = q > 256 ? 256 : q;
        const short* qp = qbase + (size_t)qc * 2048 + qh * 64;
        short8 bq0 = *(const short8*)(qp + quad * 8);
        short8 bq1 = *(const short8*)(qp + 32 + quad * 8);

        float sum = 0.f;
        f32x4 oacc[4];
        #pragma unroll
        for (int nt = 0; nt < 4; ++nt) oacc[nt] = zero4;

        #pragma unroll
        for (int c8 = 0; c8 < 9; ++c8) {
            f32x4 s0 = zero4, s1 = zero4;
            #pragma unroll
            for (int half = 0; half < 2; ++half) {
                int kt = c8 * 2 + half;
                if (kt < 17) {
                    int key = kt * 16 + l16;
                    short8 ak0 = *(const short8*)&kls[(key * 8 + c0) * 8];
                    short8 ak1 = *(const short8*)&kls[(key * 8 + (c0 ^ 4)) * 8];
                    f32x4 cc = zero4;
                    cc = __builtin_amdgcn_mfma_f32_16x16x32_bf16(ak0, bq0, cc, 0, 0, 0);
                    cc = __builtin_amdgcn_mfma_f32_16x16x32_bf16(ak1, bq1, cc, 0, 0, 0);
                    #pragma unroll
                    for (int e = 0; e < 4; ++e) {
                        float x = cc[e] * 0.0025f;           // s/50, s = dot/8
                        float x2 = x * x;
                        float v = cc[e] * 0.125f * (1.f + x2 * (-0.3333333333f + x2 * 0.1333333333f));
                        float p = __expf(v);                 // v in [-8.1, 8.1]: no overflow
                        if (kt == 16) {
                            bool valid = (e == 0) && (quad == 0) && (q == 256);
                            p = valid ? p : 0.f;
                        }
                        cc[e] = p;
                        sum += p;
                    }
                    if (half) s1 = cc; else s0 = cc;
                }
            }
            short8 pb;
            #pragma unroll
            for (int j = 0; j < 8; ++j) {
                int src_lane = ((quad & 1) * 2 + (j >> 2)) * 16 + l16;
                float v0 = __shfl(s0[j & 3], src_lane);
                float v1 = __shfl(s1[j & 3], src_lane);
                pb[j] = f2bfs(quad < 2 ? v0 : v1);
            }
            #pragma unroll
            for (int nt = 0; nt < 4; ++nt) {
                int d = nt * 16 + l16;
                int kc = (c8 * 4 + quad) ^ d7;
                short8 av = *(const short8*)&vls[(d * 40 + kc) * 8];
                oacc[nt] = __builtin_amdgcn_mfma_f32_16x16x32_bf16(pb, av, oacc[nt], 0, 0, 0);
            }
        }

        sum += __shfl_xor(sum, 16);
        sum += __shfl_xor(sum, 32);
        float inv = __builtin_amdgcn_rcpf(sum);
        f32x4 inv4;
        #pragma unroll
        for (int e = 0; e < 4; ++e) inv4[e] = __shfl(inv, quad * 4 + e);

        #pragma unroll
        for (int e = 0; e < 4; ++e) {
            int qq = qt * 16 + quad * 4 + e;
            if (qq <= 256) {
                bf16* op = ob + ((size_t)(bt * SSQ + qq)) * 1024 + qh * 64 + l16;
                float s = inv4[e];
                op[0]  = __float2bfloat16(oacc[0][e] * s);
                op[16] = __float2bfloat16(oacc[1][e] * s);
                op[32] = __float2bfloat16(oacc[2][e] * s);
                op[48] = __float2bfloat16(oacc[3][e] * s);
            }
        }
    }
}

// ---------------- time attention (n=16, causal): MFMA, one wave per (bs, qh) --------
__global__ __launch_bounds__(256)
void time_attn_kernel(const bf16* __restrict__ qkv, bf16* __restrict__ ob) {
    __shared__ __align__(16) short kls[2 * 16 * 64];    // [khl][key][8 gran], XOR-swizzled
    __shared__ __align__(16) short vls[2 * 64 * 24];    // [khl][d][key pad 24]
    int bs = blockIdx.x, qg = blockIdx.y;
    int tid = threadIdx.x, wave = tid >> 6, lane = tid & 63;
    int quad = lane >> 4, l16 = lane & 15;
    int qh = qg * 4 + wave;
    int khl_w = wave >> 1;
    size_t rowbase = (size_t)bs * 16;
    const short* qbase = (const short*)qkv;

    {
        int c = tid & 7, key = (tid >> 3) & 15, khl = tid >> 7;
        const short* ksrc = qbase + (rowbase + key) * 2048 + 1024 + (qg * 2 + khl) * 64
                            + (c ^ (key & 7)) * 8;
        async16(ksrc, &kls[((khl * 16 + key) * 8 + c) * 8]);
        short8 vv = *(const short8*)(qbase + (rowbase + key) * 2048 + 1536
                                     + (qg * 2 + khl) * 64 + c * 8);
        #pragma unroll
        for (int dd = 0; dd < 8; ++dd)
            vls[(khl * 64 + c * 8 + dd) * 24 + key] = vv[dd];
    }
    const short* qp = qbase + (rowbase + l16) * 2048 + qh * 64;
    short8 bq0 = *(const short8*)(qp + quad * 8);
    short8 bq1 = *(const short8*)(qp + 32 + quad * 8);
    __syncthreads();

    int c0 = quad ^ (l16 & 7);
    const short* kw = &kls[(khl_w * 16 + l16) * 64];
    short8 ak0 = *(const short8*)(kw + c0 * 8);
    short8 ak1 = *(const short8*)(kw + (c0 ^ 4) * 8);
    f32x4 cc = {0.f, 0.f, 0.f, 0.f};
    cc = __builtin_amdgcn_mfma_f32_16x16x32_bf16(ak0, bq0, cc, 0, 0, 0);
    cc = __builtin_amdgcn_mfma_f32_16x16x32_bf16(ak1, bq1, cc, 0, 0, 0);
    float sum = 0.f;
    #pragma unroll
    for (int e = 0; e < 4; ++e) {
        float s = cc[e] * 0.125f;
        float x = s * 0.02f, x2 = x * x;
        float v = s * (1.f + x2 * (-0.3333333333f + x2 * 0.1333333333f));
        float p = ((quad * 4 + e) > l16) ? 0.f : __expf(v);
        cc[e] = p;
        sum += p;
    }
    sum += __shfl_xor(sum, 16);
    sum += __shfl_xor(sum, 32);
    float inv = __builtin_amdgcn_rcpf(sum);
    f32x4 inv4;
    #pragma unroll
    for (int e = 0; e < 4; ++e) inv4[e] = __shfl(inv, quad * 4 + e);

    short8 pa;
    #pragma unroll
    for (int jj = 0; jj < 8; ++jj) {
        int key = quad * 8 + jj;
        int src = ((key >> 2) & 3) * 16 + l16;
        float v = __shfl(cc[jj & 3], src);
        pa[jj] = f2bfs(quad < 2 ? v : 0.f);
    }
    const short* vw = &vls[khl_w * 64 * 24];
    short8 zero8 = {0, 0, 0, 0, 0, 0, 0, 0};
    f32x4 oacc[4];
    #pragma unroll
    for (int nt = 0; nt < 4; ++nt) {
        short8 av = zero8;
        if (quad < 2)
            av = *(const short8*)(vw + (nt * 16 + l16) * 24 + quad * 8);
        f32x4 z = {0.f, 0.f, 0.f, 0.f};
        oacc[nt] = __builtin_amdgcn_mfma_f32_16x16x32_bf16(pa, av, z, 0, 0, 0);
    }
    #pragma unroll
    for (int e = 0; e < 4; ++e) {
        int q = quad * 4 + e;
        bf16* op = ob + (rowbase + q) * 1024 + qh * 64 + l16;
        float s = inv4[e];
        op[0]  = __float2bfloat16(oacc[0][e] * s);
        op[16] = __float2bfloat16(oacc[1][e] * s);
        op[32] = __float2bfloat16(oacc[2][e] * s);
        op[48] = __float2bfloat16(oacc[3][e] * s);
    }
}

// ---------------- host-side launch ----------------
extern "C" void kernel_launch(void* const* d_in, const int* in_sizes, int n_in,
                              void* d_out, int out_size, void* d_ws, size_t ws_size,
                              hipStream_t stream) {
    const float* tokens      = (const float*)d_in[0];
    const float* attn_norm_w = (const float*)d_in[1];
    const float* Wq          = (const float*)d_in[2];
    const float* Wk          = (const float*)d_in[3];
    const float* Wv          = (const float*)d_in[4];
    const float* q_gamma     = (const float*)d_in[5];
    const float* k_gamma     = (const float*)d_in[6];
    const float* Wo          = (const float*)d_in[7];
    const float* ff_norm_w   = (const float*)d_in[8];
    const float* W_in        = (const float*)d_in[9];
    const float* b_in        = (const float*)d_in[10];
    const float* W_out       = (const float*)d_in[11];
    const float* b_out       = (const float*)d_in[12];
    const float* final_w     = (const float*)d_in[13];

    float* x = (float*)d_out;
    char* ws = (char*)d_ws;

    bf16* wtqkv = (bf16*)ws;                     // [2048][512]
    bf16* wto   = wtqkv + 2048 * 512;            // [512][1024]
    bf16* wtin  = wto   + 512 * 1024;            // [2816][512] interleaved
    bf16* wtout = wtin  + 2816 * 512;            // [512][1408]
    size_t off = (size_t)(2048*512 + 512*1024 + 2816*512 + 512*1408) * 2;
    bf16* h = (bf16*)(ws + off);                 // [N][512]
    off += (size_t)NROWS * 512 * 2;
    char* region = ws + off;
    bf16* qkv = (bf16*)region;                               // [N][2048]
    bf16* glu = (bf16*)region;                               // [N][1408] (FF alias)
    bf16* ob  = (bf16*)(region + (size_t)NROWS * 2048 * 2 + (size_t)256*64*SKP*2);  // [N][1024]

    hipMemcpyAsync(x, tokens, (size_t)NROWS * 512 * 4, hipMemcpyDeviceToDevice, stream);

    for (int l = 0; l < 8; ++l) {
        int is_time = ((l + 1) % 4 == 0) ? 1 : 0;
        wtrans_layer<<<3648, 256, 0, stream>>>(
            Wq + (size_t)l * 512 * 1024, Wk + (size_t)l * 512 * 512,
            Wv + (size_t)l * 512 * 512, Wo + (size_t)l * 1024 * 512,
            W_in + (size_t)l * 512 * DI2, W_out + (size_t)l * DII * 512,
            wtqkv, wto, wtin, wtout);

        // ---- attention block ----
        rms_kernel<1><<<2056, 256, 0, stream>>>(x, attn_norm_w + (size_t)l * 512, h, is_time);
        mfma_gemm_panel<1><<<dim3(16, 16), 512, 0, stream>>>(
            h, 512, wtqkv, 512, nullptr, qkv, 2048, NROWS, 528,
            q_gamma + (size_t)l * 1024, k_gamma + (size_t)l * 512, is_time);
        if (is_time) {
            time_attn_kernel<<<dim3(514, 4), 256, 0, stream>>>(qkv, ob);
            mfma_gemm<3, 1, 64><<<dim3(4, 129), 256, 0, stream>>>(
                ob, 1024, wto, 1024, nullptr, x, 512, 512, NROWS, 1024);
        } else {
            space_attn_kernel<<<dim3(32, 8), 512, 0, stream>>>(qkv, ob);
            mfma_gemm<3, 0, 64><<<dim3(4, 129), 256, 0, stream>>>(
                ob, 1024, wto, 1024, nullptr, x, 512, 512, NROWS, 1024);
        }

        // ---- feed-forward block ----
        rms_kernel<1><<<2056, 256, 0, stream>>>(x, ff_norm_w + (size_t)l * 512, h, 0);
        mfma_gemm_panel<2><<<dim3(22, 11), 512, 0, stream>>>(
            h, 512, wtin, 512, b_in + (size_t)l * DI2, glu, GLULD, NROWS, 768,
            nullptr, nullptr, 0);
        mfma_gemm<3, 0, 64><<<dim3(4, 129), 256, 0, stream>>>(
            glu, GLULD, wtout, GLULD, b_out + (size_t)l * 512, x, 512, 512, NROWS, GLULD);
    }

    rms_kernel<0><<<2056, 256, 0, stream>>>(x, final_w, x, 0);
}